// Round 11
// baseline (1901.354 us; speedup 1.0000x reference)
//
#include <hip/hip_runtime.h>

// GraphConv: edge MLP (384->256->640, bf16 MFMA) + CSR-gather pool + obj MLP (256->256->128)
// Round 11: barrier-free streaming edge_mlp. Weights pre-packed FRAGMENT-MAJOR in global
// ([frag][lane][8 bf16] -> one coalesced 16B/lane load per MFMA B-operand, straight to VGPR;
// no LDS staging, no DMA, no per-stage barriers). A staged once to LDS (48KB, XOR-swizzled),
// H unioned over A. 3 barriers/block total. 3 blocks/CU, compiler-scheduled (no asm).

using f32x4 = __attribute__((ext_vector_type(4))) float;
using s16x8 = __attribute__((ext_vector_type(8))) short;
typedef unsigned short u16x8 __attribute__((ext_vector_type(8)));

static __device__ __forceinline__ unsigned short f2b(float f) {
    unsigned int u = __float_as_uint(f);
    unsigned int r = (u + 0x7fffu + ((u >> 16) & 1u)) >> 16;  // RNE f32->bf16
    return (unsigned short)r;
}

static __device__ __forceinline__ float b2f(unsigned short b) {
    return __uint_as_float(((unsigned)b) << 16);
}

static __device__ __forceinline__ unsigned swz(unsigned row, unsigned byteoff) {
    return byteoff ^ ((row & 7u) << 4);
}

// ---------------- weight prep: fragment-major packing ----------------
// w1aF: frag f=(((wn*4+nj)*12+ks)*64+lane), elem j: c=wn*64+nj*16+(lane&15), k=ks*32+((lane>>4)<<3)+j
// w1bF: frag f=((((nc*4+wn)*2+nj)*8+ks)*64+lane):   c=nc*128+wn*32+nj*16+(lane&15), same k
// w2aT/w2bT: plain [n][k] transpose (obj_mlp unchanged).
__global__ void prep_weights(const float* __restrict__ w1a, const float* __restrict__ w1b,
                             const float* __restrict__ w2a, const float* __restrict__ w2b,
                             unsigned short* __restrict__ w1aF, unsigned short* __restrict__ w1bF,
                             unsigned short* __restrict__ w2aT, unsigned short* __restrict__ w2bT) {
    int t = blockIdx.x * blockDim.x + threadIdx.x;
    if (t < 98304) {
        int j = t & 7; int f = t >> 3;
        int lane = f & 63; int rest = f >> 6;
        int ks = rest % 12; int rest2 = rest / 12;
        int nj = rest2 & 3; int wn = rest2 >> 2;
        int c = wn * 64 + nj * 16 + (lane & 15);
        int k = ks * 32 + ((lane >> 4) << 3) + j;
        w1aF[t] = f2b(w1a[(size_t)k * 256 + c]);
        return;
    }
    t -= 98304;
    if (t < 163840) {
        int j = t & 7; int f = t >> 3;
        int lane = f & 63; int rest = f >> 6;
        int ks = rest & 7; rest >>= 3;
        int nj = rest & 1; rest >>= 1;
        int wn = rest & 3; int nc = rest >> 2;
        int c = nc * 128 + wn * 32 + nj * 16 + (lane & 15);
        int k = ks * 32 + ((lane >> 4) << 3) + j;
        w1bF[t] = f2b(w1b[(size_t)k * 640 + c]);
        return;
    }
    t -= 163840;
    if (t < 65536) { int n = t >> 8, k = t & 255; w2aT[t] = f2b(w2a[k * 256 + n]); return; }
    t -= 65536;
    if (t < 32768) { int n = t >> 8, k = t & 255; w2bT[t] = f2b(w2b[k * 128 + n]); return; }
}

// ---------------- CSR build ----------------
__global__ void count_kernel_i(const int* __restrict__ edges, int* __restrict__ cnt, int T) {
    int e = blockIdx.x * blockDim.x + threadIdx.x;
    if (e < T) {
        atomicAdd(&cnt[edges[2 * (long long)e]], 1);
        atomicAdd(&cnt[edges[2 * (long long)e + 1]], 1);
    }
}

__global__ void scan_kernel(const int* __restrict__ cnt, int* __restrict__ rowptr,
                            int* __restrict__ cursor, int O) {
    __shared__ int sc[1024];
    const int tid = threadIdx.x;
    const int per = (O + 1023) >> 10;
    const int base = tid * per;
    int s = 0;
    for (int i = 0; i < per; ++i) { int j = base + i; if (j < O) s += cnt[j]; }
    sc[tid] = s;
    __syncthreads();
    for (int d = 1; d < 1024; d <<= 1) {
        int v = (tid >= d) ? sc[tid - d] : 0;
        __syncthreads();
        sc[tid] += v;
        __syncthreads();
    }
    int off = sc[tid] - s;
    for (int i = 0; i < per; ++i) {
        int j = base + i;
        if (j < O) { rowptr[j] = off; cursor[j] = off; off += cnt[j]; }
    }
    if (tid == 0) rowptr[O] = sc[1023];
}

__global__ void fill_kernel(const int* __restrict__ edges, int* __restrict__ cursor,
                            int* __restrict__ csr, int T) {
    int e = blockIdx.x * blockDim.x + threadIdx.x;
    if (e < T) {
        int s = edges[2 * (long long)e];
        int o = edges[2 * (long long)e + 1];
        int ps = atomicAdd(&cursor[s], 1); csr[ps] = e;
        int po = atomicAdd(&cursor[o], 1); csr[po] = T + e;
    }
}

// ---------------- edge MLP: BM=64, 4 waves, barrier-free streaming ----------------
__global__ __launch_bounds__(256, 3) void edge_mlp(
    const float* __restrict__ obj, const float* __restrict__ pred,
    const int* __restrict__ edges,
    const unsigned short* __restrict__ w1aF, const float* __restrict__ b1a,
    const unsigned short* __restrict__ w1bF, const float* __restrict__ b1b,
    unsigned short* __restrict__ edgeout, float* __restrict__ outP, int T) {
    const int m0 = blockIdx.x * 64;
    const int tid = threadIdx.x;
    const int lane = tid & 63;
    const int wn = tid >> 6;               // 4 waves: N-slice owner
    const bool evenL = ((lane & 1) == 0);

    // LDS 48KB: phase1 A [64 rows][384 k] bf16 stride 768B XOR-swizzled;
    //           phase2 H [64][256] stride 512B XOR-swizzled (first 32KB, unioned)
    __shared__ unsigned short A[24576];
    char* const ldsb = (char*)A;

    bool okR[4][4];
    #pragma unroll
    for (int mi = 0; mi < 4; ++mi)
        #pragma unroll
        for (int rr = 0; rr < 4; ++rr)
            okR[mi][rr] = (m0 + mi * 16 + ((lane >> 4) << 2) + rr) < T;

    // ---- stage A once: 64 rows x 384 k (f32 -> bf16, swizzled) ----
    {
        const int r = tid >> 2, q = tid & 3;
        int e_r = m0 + r; if (e_r >= T) e_r = T - 1;
        const float* srcs[3];
        srcs[0] = obj  + (long long)edges[2 * (long long)e_r] * 128;
        srcs[1] = pred + (long long)e_r * 128;
        srcs[2] = obj  + (long long)edges[2 * (long long)e_r + 1] * 128;
        #pragma unroll
        for (int src = 0; src < 3; ++src) {
            const float4* s4 = (const float4*)(srcs[src] + q * 32);
            #pragma unroll
            for (int i = 0; i < 8; ++i) {
                float4 v = s4[i];
                ushort4 pk; pk.x = f2b(v.x); pk.y = f2b(v.y); pk.z = f2b(v.z); pk.w = f2b(v.w);
                unsigned byte = (r * 768u + (src * 128u + q * 32u + i * 4u) * 2u) ^ ((r & 7u) << 4);
                *(ushort4*)(ldsb + byte) = pk;
            }
        }
    }
    __syncthreads();   // barrier 1 of 3

    // hoisted biases
    float bias1[4], bias2[5][2];
    #pragma unroll
    for (int nj = 0; nj < 4; ++nj) bias1[nj] = b1a[wn * 64 + nj * 16 + (lane & 15)];
    #pragma unroll
    for (int nc = 0; nc < 5; ++nc)
        #pragma unroll
        for (int nj = 0; nj < 2; ++nj)
            bias2[nc][nj] = b1b[nc * 128 + wn * 32 + nj * 16 + (lane & 15)];

    // ---- GEMM1: [64,384] x [384, 64-col slice], B-frags streamed from global ----
    f32x4 acc1[4][4];
    #pragma unroll
    for (int a = 0; a < 4; ++a)
        #pragma unroll
        for (int b = 0; b < 4; ++b) acc1[a][b] = f32x4{0.f, 0.f, 0.f, 0.f};

    {
        // frag base for (wn, nj, ks): ((wn*4+nj)*12+ks)*64*8 + lane*8
        const s16x8* fb = (const s16x8*)(w1aF) + (size_t)wn * 4 * 12 * 64 + lane;
        s16x8 bf[2][4];
        #pragma unroll
        for (int nj = 0; nj < 4; ++nj) bf[0][nj] = fb[(nj * 12 + 0) * 64];
        #pragma unroll
        for (int ks = 0; ks < 12; ++ks) {
            if (ks < 11) {
                #pragma unroll
                for (int nj = 0; nj < 4; ++nj)
                    bf[(ks + 1) & 1][nj] = fb[(nj * 12 + ks + 1) * 64];
            }
            const unsigned kk = ks * 32u + ((lane >> 4) << 3);
            s16x8 af[4];
            #pragma unroll
            for (int mi = 0; mi < 4; ++mi) {
                unsigned row = mi * 16u + (lane & 15);
                af[mi] = *(const s16x8*)(ldsb + ((row * 768u + kk * 2u) ^ ((row & 7u) << 4)));
            }
            #pragma unroll
            for (int nj = 0; nj < 4; ++nj)
                #pragma unroll
                for (int mi = 0; mi < 4; ++mi)
                    acc1[mi][nj] = __builtin_amdgcn_mfma_f32_16x16x32_bf16(af[mi], bf[ks & 1][nj], acc1[mi][nj], 0, 0, 0);
        }
    }

    __syncthreads();   // barrier 2: all A reads done before H overwrite

    // ---- H = relu(acc1 + b1a) -> LDS [64][256] swizzled ----
    #pragma unroll
    for (int nj = 0; nj < 4; ++nj) {
        unsigned col = wn * 64u + nj * 16u + (lane & 15);
        #pragma unroll
        for (int mi = 0; mi < 4; ++mi)
            #pragma unroll
            for (int rr = 0; rr < 4; ++rr) {
                unsigned row = mi * 16u + ((lane >> 4) << 2) + rr;
                float v = acc1[mi][nj][rr] + bias1[nj];
                v = v > 0.f ? v : 0.f;
                *(unsigned short*)(ldsb + ((row * 512u + col * 2u) ^ ((row & 7u) << 4))) = f2b(v);
            }
    }
    __syncthreads();   // barrier 3: H visible; GEMM2 is barrier-free

    // ---- GEMM2: 5 nc x 8 ks, B-frags streamed, epilogue per nc ----
    #pragma unroll
    for (int nc = 0; nc < 5; ++nc) {
        f32x4 acc2[4][2];
        #pragma unroll
        for (int a = 0; a < 4; ++a)
            #pragma unroll
            for (int b = 0; b < 2; ++b) acc2[a][b] = f32x4{0.f, 0.f, 0.f, 0.f};

        // frag base for (nc, wn, nj, ks): ((((nc*4+wn)*2+nj)*8+ks)*64+lane)*8
        const s16x8* fb = (const s16x8*)(w1bF) + ((size_t)(nc * 4 + wn) * 2 * 8) * 64 + lane;
        s16x8 bf[2][2];
        #pragma unroll
        for (int nj = 0; nj < 2; ++nj) bf[0][nj] = fb[(nj * 8 + 0) * 64];
        #pragma unroll
        for (int ks = 0; ks < 8; ++ks) {
            if (ks < 7) {
                #pragma unroll
                for (int nj = 0; nj < 2; ++nj)
                    bf[(ks + 1) & 1][nj] = fb[(nj * 8 + ks + 1) * 64];
            }
            const unsigned kk = ks * 32u + ((lane >> 4) << 3);
            s16x8 af[4];
            #pragma unroll
            for (int mi = 0; mi < 4; ++mi) {
                unsigned row = mi * 16u + (lane & 15);
                af[mi] = *(const s16x8*)(ldsb + ((row * 512u + kk * 2u) ^ ((row & 7u) << 4)));
            }
            #pragma unroll
            for (int nj = 0; nj < 2; ++nj)
                #pragma unroll
                for (int mi = 0; mi < 4; ++mi)
                    acc2[mi][nj] = __builtin_amdgcn_mfma_f32_16x16x32_bf16(af[mi], bf[ks & 1][nj], acc2[mi][nj], 0, 0, 0);
        }

        // epilogue nc: fire-and-forget stores
        if (nc == 2) {
            #pragma unroll
            for (int nj = 0; nj < 2; ++nj) {
                int col = nc * 128 + wn * 32 + nj * 16 + (lane & 15);
                #pragma unroll
                for (int mi = 0; mi < 4; ++mi)
                    #pragma unroll
                    for (int rr = 0; rr < 4; ++rr) {
                        int row = mi * 16 + ((lane >> 4) << 2) + rr;
                        if (okR[mi][rr]) {
                            float v = acc2[mi][nj][rr] + bias2[nc][nj];
                            v = v > 0.f ? v : 0.f;
                            outP[(long long)(m0 + row) * 128 + (col - 256)] = v;
                        }
                    }
            }
        } else {
            #pragma unroll
            for (int nj = 0; nj < 2; ++nj) {
                int col = nc * 128 + wn * 32 + nj * 16 + (lane & 15);
                int pc = (nc < 2) ? col : (col - 384);
                int pcb = (lane & 1) ? (pc - 1) : pc;
                #pragma unroll
                for (int mi = 0; mi < 4; ++mi) {
                    float vv[4];
                    #pragma unroll
                    for (int rr = 0; rr < 4; ++rr) {
                        float v = acc2[mi][nj][rr] + bias2[nc][nj];
                        vv[rr] = v > 0.f ? v : 0.f;
                    }
                    float nb0 = __shfl_xor(vv[0], 1);
                    float nb1 = __shfl_xor(vv[1], 1);
                    float nb2 = __shfl_xor(vv[2], 1);
                    float nb3 = __shfl_xor(vv[3], 1);
                    #pragma unroll
                    for (int k = 0; k < 2; ++k) {
                        float lo = evenL ? (k ? vv[1] : vv[0]) : (k ? nb3 : nb2);
                        float hi = evenL ? (k ? nb1 : nb0) : (k ? vv[3] : vv[2]);
                        int rsel = evenL ? k : 2 + k;
                        if (okR[mi][rsel]) {
                            int row = mi * 16 + ((lane >> 4) << 2) + rsel;
                            size_t e = (size_t)(m0 + row);
                            size_t rid = (nc < 2) ? e : (size_t)T + e;
                            unsigned pk = ((unsigned)f2b(hi) << 16) | f2b(lo);
                            *(unsigned*)(edgeout + rid * 256 + pcb) = pk;
                        }
                    }
                }
            }
        }
    }
}

// ---------------- CSR gather (4-row ILP) ----------------
__global__ __launch_bounds__(256, 4) void pool_gather(
    const unsigned short* __restrict__ edgeout, const int* __restrict__ rowptr,
    const int* __restrict__ csr, unsigned short* __restrict__ pooled, int O) {
    int w = blockIdx.x * 4 + (threadIdx.x >> 6);
    if (w >= O) return;
    const int lane = threadIdx.x & 63;
    const int beg = rowptr[w], end = rowptr[w + 1];
    float ax = 0.f, ay = 0.f, az = 0.f, aw = 0.f;
    float bx = 0.f, by = 0.f, bz = 0.f, bw = 0.f;
    int i = beg;
    for (; i + 3 < end; i += 4) {
        int r0 = csr[i], r1 = csr[i + 1], r2 = csr[i + 2], r3 = csr[i + 3];
        ushort4 v0 = *(const ushort4*)(edgeout + (size_t)r0 * 256 + lane * 4);
        ushort4 v1 = *(const ushort4*)(edgeout + (size_t)r1 * 256 + lane * 4);
        ushort4 v2 = *(const ushort4*)(edgeout + (size_t)r2 * 256 + lane * 4);
        ushort4 v3 = *(const ushort4*)(edgeout + (size_t)r3 * 256 + lane * 4);
        ax += b2f(v0.x); ay += b2f(v0.y); az += b2f(v0.z); aw += b2f(v0.w);
        bx += b2f(v1.x); by += b2f(v1.y); bz += b2f(v1.z); bw += b2f(v1.w);
        ax += b2f(v2.x); ay += b2f(v2.y); az += b2f(v2.z); aw += b2f(v2.w);
        bx += b2f(v3.x); by += b2f(v3.y); bz += b2f(v3.z); bw += b2f(v3.w);
    }
    for (; i < end; ++i) {
        int r0 = csr[i];
        ushort4 v0 = *(const ushort4*)(edgeout + (size_t)r0 * 256 + lane * 4);
        ax += b2f(v0.x); ay += b2f(v0.y); az += b2f(v0.z); aw += b2f(v0.w);
    }
    float inv = 1.f / fmaxf((float)(end - beg), 1.f);
    ushort4 o4;
    o4.x = f2b((ax + bx) * inv); o4.y = f2b((ay + by) * inv);
    o4.z = f2b((az + bz) * inv); o4.w = f2b((aw + bw) * inv);
    *(ushort4*)(pooled + (size_t)w * 256 + lane * 4) = o4;
}

// ---------------- object MLP ----------------
__global__ __launch_bounds__(256, 2) void obj_mlp(
    const unsigned short* __restrict__ pooled,
    const unsigned short* __restrict__ w2aT, const float* __restrict__ b2a,
    const unsigned short* __restrict__ w2bT, const float* __restrict__ b2b,
    float* __restrict__ outObj, int O) {
    const int m0 = blockIdx.x * 64;
    const int tid = threadIdx.x;
    const int lane = tid & 63, wid = tid >> 6;
    const int wm = wid >> 1, wn = wid & 1;

    __shared__ unsigned short Abuf[64 * 256];

    {
        const int r = tid >> 2, q = tid & 3;
        int objc = m0 + r; if (objc >= O) objc = O - 1;
        const u16x8* s8 = (const u16x8*)(pooled + (size_t)objc * 256);
        #pragma unroll
        for (int i = 0; i < 8; ++i) {
            u16x8 v = s8[q * 8 + i];
            unsigned byte = r * 512u + (q * 64u + i * 8u) * 2u;
            *(u16x8*)((char*)Abuf + swz(r, byte)) = v;
        }
    }
    __syncthreads();

    f32x4 acc1[2][2][4];
    #pragma unroll
    for (int a = 0; a < 2; ++a)
        #pragma unroll
        for (int b = 0; b < 2; ++b)
            #pragma unroll
            for (int c = 0; c < 4; ++c) acc1[a][b][c] = f32x4{0.f, 0.f, 0.f, 0.f};
    #pragma unroll
    for (int ks = 0; ks < 8; ++ks) {
        const int klane = ks * 32 + ((lane >> 4) << 3);
        s16x8 af[2];
        #pragma unroll
        for (int mi = 0; mi < 2; ++mi) {
            int row = wm * 32 + mi * 16 + (lane & 15);
            af[mi] = *(const s16x8*)((const char*)Abuf + swz(row, row * 512u + klane * 2u));
        }
        #pragma unroll
        for (int nb = 0; nb < 2; ++nb)
            #pragma unroll
            for (int nj = 0; nj < 4; ++nj) {
                int col = nb * 128 + wn * 64 + nj * 16 + (lane & 15);
                s16x8 bf = *(const s16x8*)(w2aT + (long long)col * 256 + klane);
                #pragma unroll
                for (int mi = 0; mi < 2; ++mi)
                    acc1[nb][mi][nj] = __builtin_amdgcn_mfma_f32_16x16x32_bf16(af[mi], bf, acc1[nb][mi][nj], 0, 0, 0);
            }
    }
    __syncthreads();

    #pragma unroll
    for (int nb = 0; nb < 2; ++nb)
        #pragma unroll
        for (int nj = 0; nj < 4; ++nj) {
            int col = nb * 128 + wn * 64 + nj * 16 + (lane & 15);
            float bias = b2a[col];
            #pragma unroll
            for (int mi = 0; mi < 2; ++mi)
                #pragma unroll
                for (int rr = 0; rr < 4; ++rr) {
                    int row = wm * 32 + mi * 16 + ((lane >> 4) << 2) + rr;
                    float v = acc1[nb][mi][nj][rr] + bias;
                    v = v > 0.f ? v : 0.f;
                    *(unsigned short*)((char*)Abuf + swz(row, row * 512u + col * 2u)) = f2b(v);
                }
        }
    __syncthreads();

    f32x4 acc2[2][4];
    #pragma unroll
    for (int b = 0; b < 2; ++b)
        #pragma unroll
        for (int c = 0; c < 4; ++c) acc2[b][c] = f32x4{0.f, 0.f, 0.f, 0.f};
    #pragma unroll
    for (int ks = 0; ks < 8; ++ks) {
        const int klane = ks * 32 + ((lane >> 4) << 3);
        s16x8 af[2];
        #pragma unroll
        for (int mi = 0; mi < 2; ++mi) {
            int row = wm * 32 + mi * 16 + (lane & 15);
            af[mi] = *(const s16x8*)((const char*)Abuf + swz(row, row * 512u + klane * 2u));
        }
        #pragma unroll
        for (int nj = 0; nj < 4; ++nj) {
            int col = wn * 64 + nj * 16 + (lane & 15);
            s16x8 bf = *(const s16x8*)(w2bT + (long long)col * 256 + klane);
            #pragma unroll
            for (int mi = 0; mi < 2; ++mi)
                acc2[mi][nj] = __builtin_amdgcn_mfma_f32_16x16x32_bf16(af[mi], bf, acc2[mi][nj], 0, 0, 0);
        }
    }

    #pragma unroll
    for (int nj = 0; nj < 4; ++nj) {
        int col = wn * 64 + nj * 16 + (lane & 15);
        float bias = b2b[col];
        #pragma unroll
        for (int mi = 0; mi < 2; ++mi)
            #pragma unroll
            for (int rr = 0; rr < 4; ++rr) {
                int row = wm * 32 + mi * 16 + ((lane >> 4) << 2) + rr;
                int o = m0 + row;
                if (o < O) {
                    float v = acc2[mi][nj][rr] + bias;
                    v = v > 0.f ? v : 0.f;
                    outObj[(long long)o * 128 + col] = v;
                }
            }
    }
}

extern "C" void kernel_launch(void* const* d_in, const int* in_sizes, int n_in,
                              void* d_out, int out_size, void* d_ws, size_t ws_size,
                              hipStream_t stream) {
    const float* obj  = (const float*)d_in[0];
    const float* pred = (const float*)d_in[1];
    const int*   edges = (const int*)d_in[2];
    const float* w1a = (const float*)d_in[3];
    const float* b1a = (const float*)d_in[4];
    const float* w1b = (const float*)d_in[5];
    const float* b1b = (const float*)d_in[6];
    const float* w2a = (const float*)d_in[7];
    const float* b2a = (const float*)d_in[8];
    const float* w2b = (const float*)d_in[9];
    const float* b2b = (const float*)d_in[10];

    const int O = in_sizes[0] / 128;
    const int T = in_sizes[1] / 128;

    auto al = [](size_t x) { return (x + 255) & ~(size_t)255; };
    const size_t szEdgeout = (size_t)2 * T * 256 * 2;
    const size_t szPooled  = (size_t)O * 256 * 2;
    const size_t szCnt     = (size_t)O * 4;
    const size_t szRow     = (size_t)(O + 1) * 4;
    const size_t szCsr     = (size_t)2 * T * 4;

    size_t off = 0;
    char* ws = (char*)d_ws;
    unsigned short* edgeout = (unsigned short*)(ws + off); off += al(szEdgeout);
    unsigned short* pooled  = (unsigned short*)(ws + off); off += al(szPooled);
    int* cnt    = (int*)(ws + off); off += al(szCnt);
    int* cursor = (int*)(ws + off); off += al(szCnt);
    int* rowptr = (int*)(ws + off); off += al(szRow);
    int* csr    = (int*)(ws + off); off += al(szCsr);
    unsigned short* w1aF = (unsigned short*)(ws + off); off += (size_t)98304 * 2;    // 192 KB frag-major
    unsigned short* w1bF = (unsigned short*)(ws + off); off += (size_t)163840 * 2;   // 320 KB frag-major
    unsigned short* w2aT = (unsigned short*)(ws + off); off += (size_t)256 * 256 * 2;
    unsigned short* w2bT = (unsigned short*)(ws + off);

    float* outObj = (float*)d_out;
    float* outP   = (float*)d_out + (size_t)O * 128;

    hipMemsetAsync(cnt, 0, szCnt, stream);
    const int prepElems = 98304 + 163840 + 65536 + 32768;
    prep_weights<<<(prepElems + 255) / 256, 256, 0, stream>>>(w1a, w1b, w2a, w2b, w1aF, w1bF, w2aT, w2bT);
    count_kernel_i<<<(T + 255) / 256, 256, 0, stream>>>(edges, cnt, T);
    scan_kernel<<<1, 1024, 0, stream>>>(cnt, rowptr, cursor, O);
    fill_kernel<<<(T + 255) / 256, 256, 0, stream>>>(edges, cursor, csr, T);
    edge_mlp<<<(T + 63) / 64, 256, 0, stream>>>(obj, pred, edges, w1aF, b1a, w1bF, b1b, edgeout, outP, T);
    pool_gather<<<(O + 3) / 4, 256, 0, stream>>>(edgeout, rowptr, csr, pooled, O);
    obj_mlp<<<(O + 63) / 64, 256, 0, stream>>>(pooled, w2aT, b2a, w2bT, b2b, outObj, O);
}

// Round 12
// 1143.435 us; speedup vs baseline: 1.6628x; 1.6628x over previous
//
#include <hip/hip_runtime.h>

// GraphConv: edge MLP (384->256->640, bf16 MFMA) + CSR-gather pool + obj MLP (256->256->128)
// Round 12: r10 memory structure (LDS-DMA'd B tiles, barrier-aligned epilogues) with
// (a) 1024 threads / 16 waves -> 4 waves/SIMD (was 2), (b) 3-buffer B rotation (160KB LDS)
// so stage s waits B(s+1) while B(s+2) flies: no mid-loop vmcnt(0) drains. Counted-vmcnt
// FIFO tables exact per stage; stores counted through barriers, drained ~2 stages late.

using f32x4 = __attribute__((ext_vector_type(4))) float;
using s16x8 = __attribute__((ext_vector_type(8))) short;
typedef unsigned short u16x8 __attribute__((ext_vector_type(8)));

#define VMCNT2  asm volatile("s_waitcnt vmcnt(2)" ::: "memory")
#define VMCNT4  asm volatile("s_waitcnt vmcnt(4)" ::: "memory")
#define VMCNT8  asm volatile("s_waitcnt vmcnt(8)" ::: "memory")
#define VMCNT10 asm volatile("s_waitcnt vmcnt(10)" ::: "memory")
#define VMCNT18 asm volatile("s_waitcnt vmcnt(18)" ::: "memory")
#define LGKM0   asm volatile("s_waitcnt lgkmcnt(0)" ::: "memory")
#define BAR     __builtin_amdgcn_s_barrier()
#define SCHEDB  __builtin_amdgcn_sched_barrier(0)

static __device__ __forceinline__ unsigned short f2b(float f) {
    unsigned int u = __float_as_uint(f);
    unsigned int r = (u + 0x7fffu + ((u >> 16) & 1u)) >> 16;  // RNE f32->bf16
    return (unsigned short)r;
}

static __device__ __forceinline__ float b2f(unsigned short b) {
    return __uint_as_float(((unsigned)b) << 16);
}

static __device__ __forceinline__ unsigned swz(unsigned row, unsigned byteoff) {
    return byteoff ^ ((row & 7u) << 4);
}

static __device__ __forceinline__ void gload_lds16(const unsigned short* g, unsigned short* l) {
    __builtin_amdgcn_global_load_lds(
        (const __attribute__((address_space(1))) unsigned int*)g,
        (__attribute__((address_space(3))) unsigned int*)l,
        16, 0, 0);
}

// ---------------- weight prep (identical to round 9/10) ----------------
// w1aT: 6 tiles [256c][64k] (32KB), byte=(c*128+kk*2)^((c&7)<<4)
// w1bT: 10 tiles [128c][128k] (32KB), byte=(c*256+kk*2)^((c&7)<<4)
__global__ void prep_weights(const float* __restrict__ w1a, const float* __restrict__ w1b,
                             const float* __restrict__ w2a, const float* __restrict__ w2b,
                             unsigned short* __restrict__ w1aT, unsigned short* __restrict__ w1bT,
                             unsigned short* __restrict__ w2aT, unsigned short* __restrict__ w2bT) {
    int t = blockIdx.x * blockDim.x + threadIdx.x;
    if (t < 6 * 16384) {
        int kt = t >> 14;
        int rem = t & 16383; int c = rem >> 6, kk = rem & 63;
        unsigned byte = ((unsigned)(c * 128 + kk * 2)) ^ ((c & 7u) << 4);
        *(unsigned short*)((char*)w1aT + (size_t)kt * 32768 + byte) =
            f2b(w1a[(size_t)(kt * 64 + kk) * 256 + c]);
        return;
    }
    t -= 98304;
    if (t < 10 * 16384) {
        int tile = t >> 14; int nc = tile >> 1, kh = tile & 1;
        int rem = t & 16383; int c = rem >> 7, kk = rem & 127;
        unsigned byte = ((unsigned)(c * 256 + kk * 2)) ^ ((c & 7u) << 4);
        *(unsigned short*)((char*)w1bT + (size_t)tile * 32768 + byte) =
            f2b(w1b[(size_t)(kh * 128 + kk) * 640 + nc * 128 + c]);
        return;
    }
    t -= 163840;
    if (t < 65536) { int n = t >> 8, k = t & 255; w2aT[t] = f2b(w2a[k * 256 + n]); return; }
    t -= 65536;
    if (t < 32768) { int n = t >> 8, k = t & 255; w2bT[t] = f2b(w2b[k * 128 + n]); return; }
}

// ---------------- CSR build ----------------
__global__ void count_kernel_i(const int* __restrict__ edges, int* __restrict__ cnt, int T) {
    int e = blockIdx.x * blockDim.x + threadIdx.x;
    if (e < T) {
        atomicAdd(&cnt[edges[2 * (long long)e]], 1);
        atomicAdd(&cnt[edges[2 * (long long)e + 1]], 1);
    }
}

__global__ void scan_kernel(const int* __restrict__ cnt, int* __restrict__ rowptr,
                            int* __restrict__ cursor, int O) {
    __shared__ int sc[1024];
    const int tid = threadIdx.x;
    const int per = (O + 1023) >> 10;
    const int base = tid * per;
    int s = 0;
    for (int i = 0; i < per; ++i) { int j = base + i; if (j < O) s += cnt[j]; }
    sc[tid] = s;
    __syncthreads();
    for (int d = 1; d < 1024; d <<= 1) {
        int v = (tid >= d) ? sc[tid - d] : 0;
        __syncthreads();
        sc[tid] += v;
        __syncthreads();
    }
    int off = sc[tid] - s;
    for (int i = 0; i < per; ++i) {
        int j = base + i;
        if (j < O) { rowptr[j] = off; cursor[j] = off; off += cnt[j]; }
    }
    if (tid == 0) rowptr[O] = sc[1023];
}

__global__ void fill_kernel(const int* __restrict__ edges, int* __restrict__ cursor,
                            int* __restrict__ csr, int T) {
    int e = blockIdx.x * blockDim.x + threadIdx.x;
    if (e < T) {
        int s = edges[2 * (long long)e];
        int o = edges[2 * (long long)e + 1];
        int ps = atomicAdd(&cursor[s], 1); csr[ps] = e;
        int po = atomicAdd(&cursor[o], 1); csr[po] = T + e;
    }
}

// ---------------- edge MLP: BM=128, 1024 threads (16 waves 2x8), 3-buf rotation ----------------
__global__ __launch_bounds__(1024, 4) void edge_mlp(
    const float* __restrict__ obj, const float* __restrict__ pred,
    const int* __restrict__ edges,
    const unsigned short* __restrict__ w1aT, const float* __restrict__ b1a,
    const unsigned short* __restrict__ w1bT, const float* __restrict__ b1b,
    unsigned short* __restrict__ edgeout, float* __restrict__ outP, int T) {
    const int m0 = blockIdx.x * 128;
    const int tid = threadIdx.x;
    const int lane = tid & 63, wid = tid >> 6;     // 0..15
    const int wm = wid >> 3, wn = wid & 7;         // 2 row-halves x 8 col-slices
    const bool evenL = ((lane & 1) == 0);

    // LDS 160 KB: [0,64K) H[128][256] swz (A dbuf 2x16KB unioned at [0,32K));
    //             [64K..160K) three 32KB B buffers, rotation index s%3
    __shared__ unsigned short U[81920];
    char* const ldsb = (char*)U;
    char* const bbase = ldsb + 65536;

    bool okR[4][4];
    #pragma unroll
    for (int mi = 0; mi < 4; ++mi)
        #pragma unroll
        for (int rr = 0; rr < 4; ++rr)
            okR[mi][rr] = (m0 + wm * 64 + mi * 16 + ((lane >> 4) << 2) + rr) < T;

    const int r = tid >> 3;   // staging row 0..127 (8 threads/row)
    const int q = tid & 7;
    int e_r = m0 + r; if (e_r >= T) e_r = T - 1;
    const int sIdx_r = edges[2 * (long long)e_r];
    const int oIdx_r = edges[2 * (long long)e_r + 1];

    // hoisted biases (no vmem in counted regions)
    float bias1[2], bias2[5];
    #pragma unroll
    for (int nj = 0; nj < 2; ++nj) bias1[nj] = b1a[wn * 32 + nj * 16 + (lane & 15)];
    #pragma unroll
    for (int nc = 0; nc < 5; ++nc) bias2[nc] = b1b[nc * 128 + wn * 16 + (lane & 15)];

    auto loadA = [&](int kt, float4* ap) {
        const float* s;
        if (kt < 2)      s = obj  + (long long)sIdx_r * 128 + kt * 64;
        else if (kt < 4) s = pred + (long long)e_r   * 128 + (kt - 2) * 64;
        else             s = obj  + (long long)oIdx_r * 128 + (kt - 4) * 64;
        const float4* s4 = (const float4*)s;
        ap[0] = s4[q * 2]; ap[1] = s4[q * 2 + 1];      // +2 vmem loads
    };

    // stage one 32KB tile: 1024 threads x 16B x 2 rounds (+2 vmcnt/thread)
    auto stage32 = [&](const unsigned short* gt, char* bb) {
        #pragma unroll
        for (int rr2 = 0; rr2 < 2; ++rr2) {
            unsigned off = wid * 2048u + rr2 * 1024u;
            gload_lds16((const unsigned short*)((const char*)gt + off + lane * 16u),
                        (unsigned short*)(bb + off));
        }
    };

    auto writeA = [&](const float4* ap, char* ab) {
        #pragma unroll
        for (int i = 0; i < 2; ++i) {
            float4 v = ap[i];
            ushort4 pk; pk.x = f2b(v.x); pk.y = f2b(v.y); pk.z = f2b(v.z); pk.w = f2b(v.w);
            unsigned byte = (r * 128u + q * 16u + i * 8u) ^ ((r & 7u) << 4);
            *(ushort4*)(ab + byte) = pk;
        }
    };

    f32x4 acc1[4][2];   // 64 rows x 32 cols per wave
    #pragma unroll
    for (int a = 0; a < 4; ++a)
        #pragma unroll
        for (int b = 0; b < 2; ++b) acc1[a][b] = f32x4{0.f, 0.f, 0.f, 0.f};

    auto mfma1 = [&](const char* ab, const char* bb) {
        #pragma unroll
        for (int ks = 0; ks < 2; ++ks) {
            const unsigned kk = ks * 32u + ((lane >> 4) << 3);
            s16x8 af[4];
            #pragma unroll
            for (int mi = 0; mi < 4; ++mi) {
                unsigned row = wm * 64u + mi * 16u + (lane & 15);
                af[mi] = *(const s16x8*)(ab + ((row * 128u + kk * 2u) ^ ((row & 7u) << 4)));
            }
            #pragma unroll
            for (int nj = 0; nj < 2; ++nj) {
                unsigned c = wn * 32u + nj * 16u + (lane & 15);
                s16x8 bf = *(const s16x8*)(bb + ((c * 128u + kk * 2u) ^ ((c & 7u) << 4)));
                #pragma unroll
                for (int mi = 0; mi < 4; ++mi)
                    acc1[mi][nj] = __builtin_amdgcn_mfma_f32_16x16x32_bf16(af[mi], bf, acc1[mi][nj], 0, 0, 0);
            }
        }
    };

    // ---- prologue: A0 -> LDS; B0,B1 in flight; A1 in flight ----
    float4 ap[2];
    loadA(0, ap);
    writeA(ap, ldsb);                         // abuf0 @ ldsb (compiler waits on ap)
    stage32(w1aT, bbase);                     // B0 -> buf0   (+2)
    stage32(w1aT + 16384, bbase + 32768);     // B1 -> buf1   (+2)
    loadA(1, ap);                             //              (+2)
    VMCNT4;                                   // B0 landed; B1+A1 flying
    LGKM0;
    BAR; SCHEDB;

    // ---- GEMM1: stages s=0..5 on tile s; issue B(s+2); wait B(s+1)+A(s+1) ----
    #pragma unroll
    for (int s = 0; s < 6; ++s) {
        char* const ab = ldsb + (s & 1) * 16384;
        // issue B(s+2): GEMM1 tiles for s+2<6, else first GEMM2 tiles
        if (s + 2 < 6) stage32(w1aT + (size_t)(s + 2) * 16384, bbase + ((s + 2) % 3) * 32768);
        else           stage32(w1bT + (size_t)(s + 2 - 6) * 16384, bbase + ((s + 2) % 3) * 32768);
        __builtin_amdgcn_s_setprio(1);
        mfma1(ab, bbase + (s % 3) * 32768);
        __builtin_amdgcn_s_setprio(0);
        VMCNT2;                               // drains B(s+1) and A(s+1); B(s+2) flies
        if (s < 5) {
            writeA(ap, ldsb + ((s + 1) & 1) * 16384);
            if (s < 4) loadA(s + 2, ap);      // +2 (A(s+2) flying across barrier)
        }
        LGKM0;
        BAR; SCHEDB;
    }

    // ---- transition: H = relu(acc1 + b1a) over the A region; B(7) in flight ----
    #pragma unroll
    for (int nj = 0; nj < 2; ++nj) {
        unsigned col = wn * 32u + nj * 16u + (lane & 15);
        #pragma unroll
        for (int mi = 0; mi < 4; ++mi)
            #pragma unroll
            for (int rr = 0; rr < 4; ++rr) {
                unsigned row = wm * 64u + mi * 16u + ((lane >> 4) << 2) + rr;
                float v = acc1[mi][nj][rr] + bias1[nj];
                v = v > 0.f ? v : 0.f;
                *(unsigned short*)(ldsb + ((row * 512u + col * 2u) ^ ((row & 7u) << 4))) = f2b(v);
            }
    }
    LGKM0;
    BAR; SCHEDB;

    // ---- GEMM2: stages s=6..15 (t10=s-6, nc=t10>>1) ----
    #pragma unroll
    for (int nc = 0; nc < 5; ++nc) {
        f32x4 acc2[4];
        #pragma unroll
        for (int a = 0; a < 4; ++a) acc2[a] = f32x4{0.f, 0.f, 0.f, 0.f};

        #pragma unroll
        for (int kh = 0; kh < 2; ++kh) {
            const int s = 6 + nc * 2 + kh;
            if (s + 2 <= 15) stage32(w1bT + (size_t)(s + 2 - 6) * 16384, bbase + ((s + 2) % 3) * 32768);
            const char* bb = bbase + (s % 3) * 32768;
            __builtin_amdgcn_s_setprio(1);
            #pragma unroll
            for (int ks = 0; ks < 4; ++ks) {
                const unsigned kkB = ks * 32u + ((lane >> 4) << 3);
                const unsigned kkH = kh * 128u + kkB;
                s16x8 af[4];
                #pragma unroll
                for (int mi = 0; mi < 4; ++mi) {
                    unsigned row = wm * 64u + mi * 16u + (lane & 15);
                    af[mi] = *(const s16x8*)(ldsb + ((row * 512u + kkH * 2u) ^ ((row & 7u) << 4)));
                }
                unsigned c = wn * 16u + (lane & 15);
                s16x8 bf = *(const s16x8*)(bb + ((c * 256u + kkB * 2u) ^ ((c & 7u) << 4)));
                #pragma unroll
                for (int mi = 0; mi < 4; ++mi)
                    acc2[mi] = __builtin_amdgcn_mfma_f32_16x16x32_bf16(af[mi], bf, acc2[mi], 0, 0, 0);
            }
            __builtin_amdgcn_s_setprio(0);

            if (kh == 0) {
                // even stage: no stores. FIFO wait table: s=6 -> VMCNT2; s=8,10 -> VMCNT10;
                // s=12 -> VMCNT18; s=14 -> VMCNT8.
                if (s == 6)       { VMCNT2; }
                else if (s == 12) { VMCNT18; }
                else if (s == 14) { VMCNT8; }
                else              { VMCNT10; }
                LGKM0; BAR; SCHEDB;
            }
        }

        // epilogue nc (odd stage end; stores newest in FIFO, counted through)
        if (nc == 2) {
            #pragma unroll
            for (int mi = 0; mi < 4; ++mi)
                #pragma unroll
                for (int rr = 0; rr < 4; ++rr) {
                    int row = wm * 64 + mi * 16 + ((lane >> 4) << 2) + rr;
                    if (okR[mi][rr]) {
                        int col = 2 * 128 + wn * 16 + (lane & 15);
                        float v = acc2[mi][rr] + bias2[2];
                        v = v > 0.f ? v : 0.f;
                        outP[(long long)(m0 + row) * 128 + (col - 256)] = v;   // +16 stores
                    }
                }
            VMCNT18;                 // s=11: drains B(12)+older; B(13)+outP fly
            LGKM0; BAR; SCHEDB;
        } else {
            #pragma unroll
            for (int mi = 0; mi < 4; ++mi) {
                int col = nc * 128 + wn * 16 + (lane & 15);
                int pc = (nc < 2) ? col : (col - 384);
                int pcb = (lane & 1) ? (pc - 1) : pc;
                float vv[4];
                #pragma unroll
                for (int rr = 0; rr < 4; ++rr) {
                    float v = acc2[mi][rr] + bias2[nc];
                    vv[rr] = v > 0.f ? v : 0.f;
                }
                float nb0 = __shfl_xor(vv[0], 1);
                float nb1 = __shfl_xor(vv[1], 1);
                float nb2 = __shfl_xor(vv[2], 1);
                float nb3 = __shfl_xor(vv[3], 1);
                #pragma unroll
                for (int k = 0; k < 2; ++k) {
                    float lo = evenL ? (k ? vv[1] : vv[0]) : (k ? nb3 : nb2);
                    float hi = evenL ? (k ? nb1 : nb0) : (k ? vv[3] : vv[2]);
                    int rsel = evenL ? k : 2 + k;
                    if (okR[mi][rsel]) {
                        int row = wm * 64 + mi * 16 + ((lane >> 4) << 2) + rsel;
                        size_t e = (size_t)(m0 + row);
                        size_t rid = (nc < 2) ? e : (size_t)T + e;
                        unsigned pk = ((unsigned)f2b(hi) << 16) | f2b(lo);
                        *(unsigned*)(edgeout + rid * 256 + pcb) = pk;          // +8 stores
                    }
                }
            }
            if (nc < 4) {            // s=7,9,13: drain B(s+1)+older; newest (B(s+2)+8 stores) fly
                VMCNT10;
                LGKM0; BAR; SCHEDB;
            }
            // nc==4 (s=15): fire-and-forget, endpgm
        }
    }
}

// ---------------- CSR gather (4-row ILP) ----------------
__global__ __launch_bounds__(256, 4) void pool_gather(
    const unsigned short* __restrict__ edgeout, const int* __restrict__ rowptr,
    const int* __restrict__ csr, unsigned short* __restrict__ pooled, int O) {
    int w = blockIdx.x * 4 + (threadIdx.x >> 6);
    if (w >= O) return;
    const int lane = threadIdx.x & 63;
    const int beg = rowptr[w], end = rowptr[w + 1];
    float ax = 0.f, ay = 0.f, az = 0.f, aw = 0.f;
    float bx = 0.f, by = 0.f, bz = 0.f, bw = 0.f;
    int i = beg;
    for (; i + 3 < end; i += 4) {
        int r0 = csr[i], r1 = csr[i + 1], r2 = csr[i + 2], r3 = csr[i + 3];
        ushort4 v0 = *(const ushort4*)(edgeout + (size_t)r0 * 256 + lane * 4);
        ushort4 v1 = *(const ushort4*)(edgeout + (size_t)r1 * 256 + lane * 4);
        ushort4 v2 = *(const ushort4*)(edgeout + (size_t)r2 * 256 + lane * 4);
        ushort4 v3 = *(const ushort4*)(edgeout + (size_t)r3 * 256 + lane * 4);
        ax += b2f(v0.x); ay += b2f(v0.y); az += b2f(v0.z); aw += b2f(v0.w);
        bx += b2f(v1.x); by += b2f(v1.y); bz += b2f(v1.z); bw += b2f(v1.w);
        ax += b2f(v2.x); ay += b2f(v2.y); az += b2f(v2.z); aw += b2f(v2.w);
        bx += b2f(v3.x); by += b2f(v3.y); bz += b2f(v3.z); bw += b2f(v3.w);
    }
    for (; i < end; ++i) {
        int r0 = csr[i];
        ushort4 v0 = *(const ushort4*)(edgeout + (size_t)r0 * 256 + lane * 4);
        ax += b2f(v0.x); ay += b2f(v0.y); az += b2f(v0.z); aw += b2f(v0.w);
    }
    float inv = 1.f / fmaxf((float)(end - beg), 1.f);
    ushort4 o4;
    o4.x = f2b((ax + bx) * inv); o4.y = f2b((ay + by) * inv);
    o4.z = f2b((az + bz) * inv); o4.w = f2b((aw + bw) * inv);
    *(ushort4*)(pooled + (size_t)w * 256 + lane * 4) = o4;
}

// ---------------- object MLP ----------------
__global__ __launch_bounds__(256, 2) void obj_mlp(
    const unsigned short* __restrict__ pooled,
    const unsigned short* __restrict__ w2aT, const float* __restrict__ b2a,
    const unsigned short* __restrict__ w2bT, const float* __restrict__ b2b,
    float* __restrict__ outObj, int O) {
    const int m0 = blockIdx.x * 64;
    const int tid = threadIdx.x;
    const int lane = tid & 63, wid = tid >> 6;
    const int wm = wid >> 1, wn = wid & 1;

    __shared__ unsigned short Abuf[64 * 256];

    {
        const int r = tid >> 2, q = tid & 3;
        int objc = m0 + r; if (objc >= O) objc = O - 1;
        const u16x8* s8 = (const u16x8*)(pooled + (size_t)objc * 256);
        #pragma unroll
        for (int i = 0; i < 8; ++i) {
            u16x8 v = s8[q * 8 + i];
            unsigned byte = r * 512u + (q * 64u + i * 8u) * 2u;
            *(u16x8*)((char*)Abuf + swz(r, byte)) = v;
        }
    }
    __syncthreads();

    f32x4 acc1[2][2][4];
    #pragma unroll
    for (int a = 0; a < 2; ++a)
        #pragma unroll
        for (int b = 0; b < 2; ++b)
            #pragma unroll
            for (int c = 0; c < 4; ++c) acc1[a][b][c] = f32x4{0.f, 0.f, 0.f, 0.f};
    #pragma unroll
    for (int ks = 0; ks < 8; ++ks) {
        const int klane = ks * 32 + ((lane >> 4) << 3);
        s16x8 af[2];
        #pragma unroll
        for (int mi = 0; mi < 2; ++mi) {
            int row = wm * 32 + mi * 16 + (lane & 15);
            af[mi] = *(const s16x8*)((const char*)Abuf + swz(row, row * 512u + klane * 2u));
        }
        #pragma unroll
        for (int nb = 0; nb < 2; ++nb)
            #pragma unroll
            for (int nj = 0; nj < 4; ++nj) {
                int col = nb * 128 + wn * 64 + nj * 16 + (lane & 15);
                s16x8 bf = *(const s16x8*)(w2aT + (long long)col * 256 + klane);
                #pragma unroll
                for (int mi = 0; mi < 2; ++mi)
                    acc1[nb][mi][nj] = __builtin_amdgcn_mfma_f32_16x16x32_bf16(af[mi], bf, acc1[nb][mi][nj], 0, 0, 0);
            }
    }
    __syncthreads();

    #pragma unroll
    for (int nb = 0; nb < 2; ++nb)
        #pragma unroll
        for (int nj = 0; nj < 4; ++nj) {
            int col = nb * 128 + wn * 64 + nj * 16 + (lane & 15);
            float bias = b2a[col];
            #pragma unroll
            for (int mi = 0; mi < 2; ++mi)
                #pragma unroll
                for (int rr = 0; rr < 4; ++rr) {
                    int row = wm * 32 + mi * 16 + ((lane >> 4) << 2) + rr;
                    float v = acc1[nb][mi][nj][rr] + bias;
                    v = v > 0.f ? v : 0.f;
                    *(unsigned short*)((char*)Abuf + swz(row, row * 512u + col * 2u)) = f2b(v);
                }
        }
    __syncthreads();

    f32x4 acc2[2][4];
    #pragma unroll
    for (int b = 0; b < 2; ++b)
        #pragma unroll
        for (int c = 0; c < 4; ++c) acc2[b][c] = f32x4{0.f, 0.f, 0.f, 0.f};
    #pragma unroll
    for (int ks = 0; ks < 8; ++ks) {
        const int klane = ks * 32 + ((lane >> 4) << 3);
        s16x8 af[2];
        #pragma unroll
        for (int mi = 0; mi < 2; ++mi) {
            int row = wm * 32 + mi * 16 + (lane & 15);
            af[mi] = *(const s16x8*)((const char*)Abuf + swz(row, row * 512u + klane * 2u));
        }
        #pragma unroll
        for (int nj = 0; nj < 4; ++nj) {
            int col = wn * 64 + nj * 16 + (lane & 15);
            s16x8 bf = *(const s16x8*)(w2bT + (long long)col * 256 + klane);
            #pragma unroll
            for (int mi = 0; mi < 2; ++mi)
                acc2[mi][nj] = __builtin_amdgcn_mfma_f32_16x16x32_bf16(af[mi], bf, acc2[mi][nj], 0, 0, 0);
        }
    }

    #pragma unroll
    for (int nj = 0; nj < 4; ++nj) {
        int col = wn * 64 + nj * 16 + (lane & 15);
        float bias = b2b[col];
        #pragma unroll
        for (int mi = 0; mi < 2; ++mi)
            #pragma unroll
            for (int rr = 0; rr < 4; ++rr) {
                int row = wm * 32 + mi * 16 + ((lane >> 4) << 2) + rr;
                int o = m0 + row;
                if (o < O) {
                    float v = acc2[mi][nj][rr] + bias;
                    v = v > 0.f ? v : 0.f;
                    outObj[(long long)o * 128 + col] = v;
                }
            }
    }
}

extern "C" void kernel_launch(void* const* d_in, const int* in_sizes, int n_in,
                              void* d_out, int out_size, void* d_ws, size_t ws_size,
                              hipStream_t stream) {
    const float* obj  = (const float*)d_in[0];
    const float* pred = (const float*)d_in[1];
    const int*   edges = (const int*)d_in[2];
    const float* w1a = (const float*)d_in[3];
    const float* b1a = (const float*)d_in[4];
    const float* w1b = (const float*)d_in[5];
    const float* b1b = (const float*)d_in[6];
    const float* w2a = (const float*)d_in[7];
    const float* b2a = (const float*)d_in[8];
    const float* w2b = (const float*)d_in[9];
    const float* b2b = (const float*)d_in[10];

    const int O = in_sizes[0] / 128;
    const int T = in_sizes[1] / 128;

    auto al = [](size_t x) { return (x + 255) & ~(size_t)255; };
    const size_t szEdgeout = (size_t)2 * T * 256 * 2;
    const size_t szPooled  = (size_t)O * 256 * 2;
    const size_t szCnt     = (size_t)O * 4;
    const size_t szRow     = (size_t)(O + 1) * 4;
    const size_t szCsr     = (size_t)2 * T * 4;

    size_t off = 0;
    char* ws = (char*)d_ws;
    unsigned short* edgeout = (unsigned short*)(ws + off); off += al(szEdgeout);
    unsigned short* pooled  = (unsigned short*)(ws + off); off += al(szPooled);
    int* cnt    = (int*)(ws + off); off += al(szCnt);
    int* cursor = (int*)(ws + off); off += al(szCnt);
    int* rowptr = (int*)(ws + off); off += al(szRow);
    int* csr    = (int*)(ws + off); off += al(szCsr);
    unsigned short* w1aT = (unsigned short*)(ws + off); off += (size_t)6 * 16384 * 2;
    unsigned short* w1bT = (unsigned short*)(ws + off); off += (size_t)10 * 16384 * 2;
    unsigned short* w2aT = (unsigned short*)(ws + off); off += (size_t)256 * 256 * 2;
    unsigned short* w2bT = (unsigned short*)(ws + off);

    float* outObj = (float*)d_out;
    float* outP   = (float*)d_out + (size_t)O * 128;

    hipMemsetAsync(cnt, 0, szCnt, stream);
    const int prepElems = 98304 + 163840 + 65536 + 32768;
    prep_weights<<<(prepElems + 255) / 256, 256, 0, stream>>>(w1a, w1b, w2a, w2b, w1aT, w1bT, w2aT, w2bT);
    count_kernel_i<<<(T + 255) / 256, 256, 0, stream>>>(edges, cnt, T);
    scan_kernel<<<1, 1024, 0, stream>>>(cnt, rowptr, cursor, O);
    fill_kernel<<<(T + 255) / 256, 256, 0, stream>>>(edges, cursor, csr, T);
    edge_mlp<<<(T + 127) / 128, 1024, 0, stream>>>(obj, pred, edges, w1aT, b1a, w1bT, b1b, edgeout, outP, T);
    pool_gather<<<(O + 3) / 4, 256, 0, stream>>>(edgeout, rowptr, csr, pooled, O);
    obj_mlp<<<(O + 63) / 64, 256, 0, stream>>>(pooled, w2aT, b2a, w2bT, b2b, outObj, O);
}

// Round 13
// 917.125 us; speedup vs baseline: 2.0732x; 1.2468x over previous
//
#include <hip/hip_runtime.h>

// GraphConv: edge MLP (384->256->640, bf16 MFMA) + slot-direct CSR pool + obj MLP (256->256->128)
// Round 13: (a) r10 geometry (512 thr, 8 waves, VGPR-safe) + 3-buffer B rotation: stage s
// issues B(s+2), waits B(s+1) -> every DMA covered by a full stage+barrier; no vmcnt(0) drains.
// (b) slot-direct pooling: edge_mlp writes new_s/new_o rows at their CSR slot (slotS/slotO
// precomputed) -> pool_gather reads CONTIGUOUS ranges (was random 512B rows); csr[] deleted.

using f32x4 = __attribute__((ext_vector_type(4))) float;
using s16x8 = __attribute__((ext_vector_type(8))) short;
typedef unsigned short u16x8 __attribute__((ext_vector_type(8)));

#define VMCNT4  asm volatile("s_waitcnt vmcnt(4)" ::: "memory")
#define VMCNT8  asm volatile("s_waitcnt vmcnt(8)" ::: "memory")
#define VMCNT16 asm volatile("s_waitcnt vmcnt(16)" ::: "memory")
#define VMCNT20 asm volatile("s_waitcnt vmcnt(20)" ::: "memory")
#define VMCNT36 asm volatile("s_waitcnt vmcnt(36)" ::: "memory")
#define LGKM0   asm volatile("s_waitcnt lgkmcnt(0)" ::: "memory")
#define BAR     __builtin_amdgcn_s_barrier()
#define SCHEDB  __builtin_amdgcn_sched_barrier(0)

static __device__ __forceinline__ unsigned short f2b(float f) {
    unsigned int u = __float_as_uint(f);
    unsigned int r = (u + 0x7fffu + ((u >> 16) & 1u)) >> 16;  // RNE f32->bf16
    return (unsigned short)r;
}

static __device__ __forceinline__ float b2f(unsigned short b) {
    return __uint_as_float(((unsigned)b) << 16);
}

static __device__ __forceinline__ unsigned swz(unsigned row, unsigned byteoff) {
    return byteoff ^ ((row & 7u) << 4);
}

static __device__ __forceinline__ void gload_lds16(const unsigned short* g, unsigned short* l) {
    __builtin_amdgcn_global_load_lds(
        (const __attribute__((address_space(1))) unsigned int*)g,
        (__attribute__((address_space(3))) unsigned int*)l,
        16, 0, 0);
}

// ---------------- weight prep (identical to rounds 9/10) ----------------
// w1aT: 6 tiles [256c][64k] (32KB), byte=(c*128+kk*2)^((c&7)<<4)
// w1bT: 10 tiles [128c][128k] (32KB), byte=(c*256+kk*2)^((c&7)<<4)
__global__ void prep_weights(const float* __restrict__ w1a, const float* __restrict__ w1b,
                             const float* __restrict__ w2a, const float* __restrict__ w2b,
                             unsigned short* __restrict__ w1aT, unsigned short* __restrict__ w1bT,
                             unsigned short* __restrict__ w2aT, unsigned short* __restrict__ w2bT) {
    int t = blockIdx.x * blockDim.x + threadIdx.x;
    if (t < 6 * 16384) {
        int kt = t >> 14;
        int rem = t & 16383; int c = rem >> 6, kk = rem & 63;
        unsigned byte = ((unsigned)(c * 128 + kk * 2)) ^ ((c & 7u) << 4);
        *(unsigned short*)((char*)w1aT + (size_t)kt * 32768 + byte) =
            f2b(w1a[(size_t)(kt * 64 + kk) * 256 + c]);
        return;
    }
    t -= 98304;
    if (t < 10 * 16384) {
        int tile = t >> 14; int nc = tile >> 1, kh = tile & 1;
        int rem = t & 16383; int c = rem >> 7, kk = rem & 127;
        unsigned byte = ((unsigned)(c * 256 + kk * 2)) ^ ((c & 7u) << 4);
        *(unsigned short*)((char*)w1bT + (size_t)tile * 32768 + byte) =
            f2b(w1b[(size_t)(kh * 128 + kk) * 640 + nc * 128 + c]);
        return;
    }
    t -= 163840;
    if (t < 65536) { int n = t >> 8, k = t & 255; w2aT[t] = f2b(w2a[k * 256 + n]); return; }
    t -= 65536;
    if (t < 32768) { int n = t >> 8, k = t & 255; w2bT[t] = f2b(w2b[k * 128 + n]); return; }
}

// ---------------- CSR build ----------------
__global__ void count_kernel_i(const int* __restrict__ edges, int* __restrict__ cnt, int T) {
    int e = blockIdx.x * blockDim.x + threadIdx.x;
    if (e < T) {
        atomicAdd(&cnt[edges[2 * (long long)e]], 1);
        atomicAdd(&cnt[edges[2 * (long long)e + 1]], 1);
    }
}

__global__ void scan_kernel(const int* __restrict__ cnt, int* __restrict__ rowptr,
                            int* __restrict__ cursor, int O) {
    __shared__ int sc[1024];
    const int tid = threadIdx.x;
    const int per = (O + 1023) >> 10;
    const int base = tid * per;
    int s = 0;
    for (int i = 0; i < per; ++i) { int j = base + i; if (j < O) s += cnt[j]; }
    sc[tid] = s;
    __syncthreads();
    for (int d = 1; d < 1024; d <<= 1) {
        int v = (tid >= d) ? sc[tid - d] : 0;
        __syncthreads();
        sc[tid] += v;
        __syncthreads();
    }
    int off = sc[tid] - s;
    for (int i = 0; i < per; ++i) {
        int j = base + i;
        if (j < O) { rowptr[j] = off; cursor[j] = off; off += cnt[j]; }
    }
    if (tid == 0) rowptr[O] = sc[1023];
}

// per-edge CSR slots (no csr array): slotS[e], slotO[e]
__global__ void slot_kernel(const int* __restrict__ edges, int* __restrict__ cursor,
                            int* __restrict__ slotS, int* __restrict__ slotO, int T) {
    int e = blockIdx.x * blockDim.x + threadIdx.x;
    if (e < T) {
        int s = edges[2 * (long long)e];
        int o = edges[2 * (long long)e + 1];
        slotS[e] = atomicAdd(&cursor[s], 1);
        slotO[e] = atomicAdd(&cursor[o], 1);
    }
}

// ---------------- edge MLP: BM=128, 512 thr (8 waves 2x4), 3-buf rotation ----------------
__global__ __launch_bounds__(512, 2) void edge_mlp(
    const float* __restrict__ obj, const float* __restrict__ pred,
    const int* __restrict__ edges,
    const unsigned short* __restrict__ w1aT, const float* __restrict__ b1a,
    const unsigned short* __restrict__ w1bT, const float* __restrict__ b1b,
    const int* __restrict__ slotS, const int* __restrict__ slotO,
    unsigned short* __restrict__ edgeout, float* __restrict__ outP, int T) {
    const int m0 = blockIdx.x * 128;
    const int tid = threadIdx.x;
    const int lane = tid & 63, wid = tid >> 6;
    const int wm = wid >> 2, wn = wid & 3;
    const bool evenL = ((lane & 1) == 0);

    // LDS 160 KB: [0,64K) H[128][256] swz (A dbuf 2x16KB unioned at [0,32K));
    //             [64K,160K) three 32KB B buffers, rotation idx s%3
    __shared__ unsigned short U[81920];
    char* const ldsb = (char*)U;
    char* const bbase = ldsb + 65536;

    bool okR[4][4];
    #pragma unroll
    for (int mi = 0; mi < 4; ++mi)
        #pragma unroll
        for (int rr = 0; rr < 4; ++rr)
            okR[mi][rr] = (m0 + wm * 64 + mi * 16 + ((lane >> 4) << 2) + rr) < T;

    // CSR slots for this lane's 8 epilogue rows (oldest in vmcnt FIFO -> counted waits safe)
    int slotSr[4][2], slotOr[4][2];
    #pragma unroll
    for (int mi = 0; mi < 4; ++mi)
        #pragma unroll
        for (int k = 0; k < 2; ++k) {
            int rsel = evenL ? k : 2 + k;
            int e = m0 + wm * 64 + mi * 16 + ((lane >> 4) << 2) + rsel;
            if (e >= T) e = T - 1;
            slotSr[mi][k] = slotS[e];
            slotOr[mi][k] = slotO[e];
        }

    const int r = tid >> 2;   // staging row 0..127
    const int q = tid & 3;
    int e_r = m0 + r; if (e_r >= T) e_r = T - 1;
    const int sIdx_r = edges[2 * (long long)e_r];
    const int oIdx_r = edges[2 * (long long)e_r + 1];

    // hoisted biases
    float bias1[4], bias2[5][2];
    #pragma unroll
    for (int nj = 0; nj < 4; ++nj) bias1[nj] = b1a[wn * 64 + nj * 16 + (lane & 15)];
    #pragma unroll
    for (int nc = 0; nc < 5; ++nc)
        #pragma unroll
        for (int nj = 0; nj < 2; ++nj)
            bias2[nc][nj] = b1b[nc * 128 + wn * 32 + nj * 16 + (lane & 15)];

    auto aSrc = [&](int kt) -> const float4* {
        const float* s;
        if (kt < 2)      s = obj  + (long long)sIdx_r * 128 + kt * 64;
        else if (kt < 4) s = pred + (long long)e_r   * 128 + (kt - 2) * 64;
        else             s = obj  + (long long)oIdx_r * 128 + (kt - 4) * 64;
        return (const float4*)s;
    };

    // unified tile pointer: 0..5 = w1aT tiles, 6..15 = w1bT tiles
    auto tp = [&](int i) -> const unsigned short* {
        return (i < 6) ? (w1aT + (size_t)i * 16384) : (w1bT + (size_t)(i - 6) * 16384);
    };

    auto stage32 = [&](const unsigned short* gt, char* bb) {
        #pragma unroll
        for (int rr4 = 0; rr4 < 4; ++rr4) {
            unsigned off = wid * 4096u + rr4 * 1024u;
            gload_lds16((const unsigned short*)((const char*)gt + off + lane * 16u),
                        (unsigned short*)(bb + off));
        }
    };

    auto writeA = [&](const float4* ap, char* ab) {
        #pragma unroll
        for (int i = 0; i < 4; ++i) {
            float4 v = ap[i];
            ushort4 pk; pk.x = f2b(v.x); pk.y = f2b(v.y); pk.z = f2b(v.z); pk.w = f2b(v.w);
            unsigned byte = (r * 128u + q * 32u + i * 8u) ^ ((r & 7u) << 4);
            *(ushort4*)(ab + byte) = pk;
        }
    };

    f32x4 acc1[4][4];
    #pragma unroll
    for (int a = 0; a < 4; ++a)
        #pragma unroll
        for (int b = 0; b < 4; ++b) acc1[a][b] = f32x4{0.f, 0.f, 0.f, 0.f};

    auto mfma1 = [&](const char* ab, const char* bb) {
        #pragma unroll
        for (int ks = 0; ks < 2; ++ks) {
            const unsigned kk = ks * 32u + ((lane >> 4) << 3);
            s16x8 af[4];
            #pragma unroll
            for (int mi = 0; mi < 4; ++mi) {
                unsigned row = wm * 64u + mi * 16u + (lane & 15);
                af[mi] = *(const s16x8*)(ab + ((row * 128u + kk * 2u) ^ ((row & 7u) << 4)));
            }
            #pragma unroll
            for (int nj = 0; nj < 4; ++nj) {
                unsigned c = wn * 64u + nj * 16u + (lane & 15);
                s16x8 bf = *(const s16x8*)(bb + ((c * 128u + kk * 2u) ^ ((c & 7u) << 4)));
                #pragma unroll
                for (int mi = 0; mi < 4; ++mi)
                    acc1[mi][nj] = __builtin_amdgcn_mfma_f32_16x16x32_bf16(af[mi], bf, acc1[mi][nj], 0, 0, 0);
            }
        }
    };

    // ---- prologue: A0->LDS; B0,B1 in flight; A1 in flight ----
    float4 ap[4];
    {
        const float4* s4 = aSrc(0);
        #pragma unroll
        for (int i = 0; i < 4; ++i) ap[i] = s4[q * 4 + i];
    }
    writeA(ap, ldsb);                       // abuf0 (compiler drains A0)
    stage32(tp(0), bbase);                  // B0 -> buf0 (+4)
    stage32(tp(1), bbase + 32768);          // B1 -> buf1 (+4)
    {
        const float4* s4 = aSrc(1);
        #pragma unroll
        for (int i = 0; i < 4; ++i) ap[i] = s4[q * 4 + i];   // A1 (+4)
    }
    VMCNT8;                                 // B0 landed; B1+A1 fly
    LGKM0; BAR; SCHEDB;

    // ---- GEMM1 stages s=0..5: compute B(s), issue B(s+2), wait B(s+1)+A(s+1) ----
    #pragma unroll
    for (int s = 0; s < 6; ++s) {
        stage32(tp(s + 2), bbase + ((s + 2) % 3) * 32768);   // +4, 2 stages ahead
        __builtin_amdgcn_s_setprio(1);
        mfma1(ldsb + (s & 1) * 16384, bbase + (s % 3) * 32768);
        __builtin_amdgcn_s_setprio(0);
        VMCNT4;                             // B(s+1) [+A(s+1) if s<5] done; B(s+2) flies
        if (s < 5) {
            writeA(ap, ldsb + ((s + 1) & 1) * 16384);
            if (s < 4) {
                const float4* s4 = aSrc(s + 2);
                #pragma unroll
                for (int i = 0; i < 4; ++i) ap[i] = s4[q * 4 + i];   // A(s+2) (+4)
            }
        }
        LGKM0; BAR; SCHEDB;
    }

    // ---- transition: H = relu(acc1+b1a) over [0,64K); B7 still in flight ----
    #pragma unroll
    for (int nj = 0; nj < 4; ++nj) {
        unsigned col = wn * 64u + nj * 16u + (lane & 15);
        #pragma unroll
        for (int mi = 0; mi < 4; ++mi)
            #pragma unroll
            for (int rr = 0; rr < 4; ++rr) {
                unsigned row = wm * 64u + mi * 16u + ((lane >> 4) << 2) + rr;
                float v = acc1[mi][nj][rr] + bias1[nj];
                v = v > 0.f ? v : 0.f;
                *(unsigned short*)(ldsb + ((row * 512u + col * 2u) ^ ((row & 7u) << 4))) = f2b(v);
            }
    }
    LGKM0; BAR; SCHEDB;

    // ---- GEMM2 stages s=6..15 (consume tiles 6..15); wait table per FIFO simulation ----
    #pragma unroll
    for (int nc = 0; nc < 5; ++nc) {
        f32x4 acc2[4][2];
        #pragma unroll
        for (int a = 0; a < 4; ++a)
            #pragma unroll
            for (int b = 0; b < 2; ++b) acc2[a][b] = f32x4{0.f, 0.f, 0.f, 0.f};

        #pragma unroll
        for (int kh = 0; kh < 2; ++kh) {
            const int s = 6 + nc * 2 + kh;
            if (s + 2 <= 15) stage32(tp(s + 2), bbase + ((s + 2) % 3) * 32768);   // +4
            const char* bb = bbase + (s % 3) * 32768;
            __builtin_amdgcn_s_setprio(1);
            #pragma unroll
            for (int ks = 0; ks < 4; ++ks) {
                const unsigned kkB = ks * 32u + ((lane >> 4) << 3);
                const unsigned kkH = (kh * 128u) + kkB;
                s16x8 af[4];
                #pragma unroll
                for (int mi = 0; mi < 4; ++mi) {
                    unsigned row = wm * 64u + mi * 16u + (lane & 15);
                    af[mi] = *(const s16x8*)(ldsb + ((row * 512u + kkH * 2u) ^ ((row & 7u) << 4)));
                }
                #pragma unroll
                for (int nj = 0; nj < 2; ++nj) {
                    unsigned c = wn * 32u + nj * 16u + (lane & 15);
                    s16x8 bf = *(const s16x8*)(bb + ((c * 256u + kkB * 2u) ^ ((c & 7u) << 4)));
                    #pragma unroll
                    for (int mi = 0; mi < 4; ++mi)
                        acc2[mi][nj] = __builtin_amdgcn_mfma_f32_16x16x32_bf16(af[mi], bf, acc2[mi][nj], 0, 0, 0);
                }
            }
            __builtin_amdgcn_s_setprio(0);

            if (kh == 0) {
                // stage-end wait (no stores this stage): s=6->4; s=8,10->20; s=12->36; s=14->16
                if (s == 6)       { VMCNT4; }
                else if (s == 12) { VMCNT36; }
                else if (s == 14) { VMCNT16; }
                else              { VMCNT20; }
                LGKM0; BAR; SCHEDB;
            }
        }

        // epilogue for nc (after kh=1 stage's mfma; stores newest in FIFO)
        if (nc == 2) {
            #pragma unroll
            for (int nj = 0; nj < 2; ++nj) {
                int col = 2 * 128 + wn * 32 + nj * 16 + (lane & 15);
                #pragma unroll
                for (int mi = 0; mi < 4; ++mi)
                    #pragma unroll
                    for (int rr = 0; rr < 4; ++rr) {
                        int row = wm * 64 + mi * 16 + ((lane >> 4) << 2) + rr;
                        if (okR[mi][rr]) {
                            float v = acc2[mi][nj][rr] + bias2[2][nj];
                            v = v > 0.f ? v : 0.f;
                            outP[(long long)(m0 + row) * 128 + (col - 256)] = v;   // +32 stores
                        }
                    }
            }
            VMCNT36;   // s=11: drain B12; leaves B13,B14? (per table) + stores
            LGKM0; BAR; SCHEDB;
        } else {
            #pragma unroll
            for (int nj = 0; nj < 2; ++nj) {
                int col = nc * 128 + wn * 32 + nj * 16 + (lane & 15);
                int pc = (nc < 2) ? col : (col - 384);
                int pcb = (lane & 1) ? (pc - 1) : pc;
                #pragma unroll
                for (int mi = 0; mi < 4; ++mi) {
                    float vv[4];
                    #pragma unroll
                    for (int rr = 0; rr < 4; ++rr) {
                        float v = acc2[mi][nj][rr] + bias2[nc][nj];
                        vv[rr] = v > 0.f ? v : 0.f;
                    }
                    float nb0 = __shfl_xor(vv[0], 1);
                    float nb1 = __shfl_xor(vv[1], 1);
                    float nb2 = __shfl_xor(vv[2], 1);
                    float nb3 = __shfl_xor(vv[3], 1);
                    #pragma unroll
                    for (int k = 0; k < 2; ++k) {
                        float lo = evenL ? (k ? vv[1] : vv[0]) : (k ? nb3 : nb2);
                        float hi = evenL ? (k ? nb1 : nb0) : (k ? vv[3] : vv[2]);
                        int rsel = evenL ? k : 2 + k;
                        if (okR[mi][rsel]) {
                            int slot = (nc < 2) ? slotSr[mi][k] : slotOr[mi][k];
                            unsigned pk = ((unsigned)f2b(hi) << 16) | f2b(lo);
                            *(unsigned*)(edgeout + (size_t)slot * 256 + pcb) = pk;  // +16 stores
                        }
                    }
                }
            }
            if (nc < 4) {            // s=7,9 -> 20; s=13 -> 20
                VMCNT20;
                LGKM0; BAR; SCHEDB;
            }
            // nc==4 (s=15): fire-and-forget, endpgm
        }
    }
}

// ---------------- pool: contiguous CSR ranges (slot-direct edgeout) ----------------
__global__ __launch_bounds__(256, 4) void pool_gather(
    const unsigned short* __restrict__ edgeout, const int* __restrict__ rowptr,
    unsigned short* __restrict__ pooled, int O) {
    int w = blockIdx.x * 4 + (threadIdx.x >> 6);
    if (w >= O) return;
    const int lane = threadIdx.x & 63;
    const int beg = rowptr[w], end = rowptr[w + 1];
    float ax = 0.f, ay = 0.f, az = 0.f, aw = 0.f;
    float bx = 0.f, by = 0.f, bz = 0.f, bw = 0.f;
    const unsigned short* base = edgeout + (size_t)beg * 256 + lane * 4;
    int n = end - beg;
    int i = 0;
    for (; i + 3 < n; i += 4) {
        ushort4 v0 = *(const ushort4*)(base + (size_t)(i    ) * 256);
        ushort4 v1 = *(const ushort4*)(base + (size_t)(i + 1) * 256);
        ushort4 v2 = *(const ushort4*)(base + (size_t)(i + 2) * 256);
        ushort4 v3 = *(const ushort4*)(base + (size_t)(i + 3) * 256);
        ax += b2f(v0.x); ay += b2f(v0.y); az += b2f(v0.z); aw += b2f(v0.w);
        bx += b2f(v1.x); by += b2f(v1.y); bz += b2f(v1.z); bw += b2f(v1.w);
        ax += b2f(v2.x); ay += b2f(v2.y); az += b2f(v2.z); aw += b2f(v2.w);
        bx += b2f(v3.x); by += b2f(v3.y); bz += b2f(v3.z); bw += b2f(v3.w);
    }
    for (; i < n; ++i) {
        ushort4 v0 = *(const ushort4*)(base + (size_t)i * 256);
        ax += b2f(v0.x); ay += b2f(v0.y); az += b2f(v0.z); aw += b2f(v0.w);
    }
    float inv = 1.f / fmaxf((float)n, 1.f);
    ushort4 o4;
    o4.x = f2b((ax + bx) * inv); o4.y = f2b((ay + by) * inv);
    o4.z = f2b((az + bz) * inv); o4.w = f2b((aw + bw) * inv);
    *(ushort4*)(pooled + (size_t)w * 256 + lane * 4) = o4;
}

// ---------------- object MLP (pooled pre-normalized) ----------------
__global__ __launch_bounds__(256, 2) void obj_mlp(
    const unsigned short* __restrict__ pooled,
    const unsigned short* __restrict__ w2aT, const float* __restrict__ b2a,
    const unsigned short* __restrict__ w2bT, const float* __restrict__ b2b,
    float* __restrict__ outObj, int O) {
    const int m0 = blockIdx.x * 64;
    const int tid = threadIdx.x;
    const int lane = tid & 63, wid = tid >> 6;
    const int wm = wid >> 1, wn = wid & 1;

    __shared__ unsigned short Abuf[64 * 256];

    {
        const int r = tid >> 2, q = tid & 3;
        int objc = m0 + r; if (objc >= O) objc = O - 1;
        const u16x8* s8 = (const u16x8*)(pooled + (size_t)objc * 256);
        #pragma unroll
        for (int i = 0; i < 8; ++i) {
            u16x8 v = s8[q * 8 + i];
            unsigned byte = r * 512u + (q * 64u + i * 8u) * 2u;
            *(u16x8*)((char*)Abuf + swz(r, byte)) = v;
        }
    }
    __syncthreads();

    f32x4 acc1[2][2][4];
    #pragma unroll
    for (int a = 0; a < 2; ++a)
        #pragma unroll
        for (int b = 0; b < 2; ++b)
            #pragma unroll
            for (int c = 0; c < 4; ++c) acc1[a][b][c] = f32x4{0.f, 0.f, 0.f, 0.f};
    #pragma unroll
    for (int ks = 0; ks < 8; ++ks) {
        const int klane = ks * 32 + ((lane >> 4) << 3);
        s16x8 af[2];
        #pragma unroll
        for (int mi = 0; mi < 2; ++mi) {
            int row = wm * 32 + mi * 16 + (lane & 15);
            af[mi] = *(const s16x8*)((const char*)Abuf + swz(row, row * 512u + klane * 2u));
        }
        #pragma unroll
        for (int nb = 0; nb < 2; ++nb)
            #pragma unroll
            for (int nj = 0; nj < 4; ++nj) {
                int col = nb * 128 + wn * 64 + nj * 16 + (lane & 15);
                s16x8 bf = *(const s16x8*)(w2aT + (long long)col * 256 + klane);
                #pragma unroll
                for (int mi = 0; mi < 2; ++mi)
                    acc1[nb][mi][nj] = __builtin_amdgcn_mfma_f32_16x16x32_bf16(af[mi], bf, acc1[nb][mi][nj], 0, 0, 0);
            }
    }
    __syncthreads();

    #pragma unroll
    for (int nb = 0; nb < 2; ++nb)
        #pragma unroll
        for (int nj = 0; nj < 4; ++nj) {
            int col = nb * 128 + wn * 64 + nj * 16 + (lane & 15);
            float bias = b2a[col];
            #pragma unroll
            for (int mi = 0; mi < 2; ++mi)
                #pragma unroll
                for (int rr = 0; rr < 4; ++rr) {
                    int row = wm * 32 + mi * 16 + ((lane >> 4) << 2) + rr;
                    float v = acc1[nb][mi][nj][rr] + bias;
                    v = v > 0.f ? v : 0.f;
                    *(unsigned short*)((char*)Abuf + swz(row, row * 512u + col * 2u)) = f2b(v);
                }
        }
    __syncthreads();

    f32x4 acc2[2][4];
    #pragma unroll
    for (int b = 0; b < 2; ++b)
        #pragma unroll
        for (int c = 0; c < 4; ++c) acc2[b][c] = f32x4{0.f, 0.f, 0.f, 0.f};
    #pragma unroll
    for (int ks = 0; ks < 8; ++ks) {
        const int klane = ks * 32 + ((lane >> 4) << 3);
        s16x8 af[2];
        #pragma unroll
        for (int mi = 0; mi < 2; ++mi) {
            int row = wm * 32 + mi * 16 + (lane & 15);
            af[mi] = *(const s16x8*)((const char*)Abuf + swz(row, row * 512u + klane * 2u));
        }
        #pragma unroll
        for (int nj = 0; nj < 4; ++nj) {
            int col = wn * 64 + nj * 16 + (lane & 15);
            s16x8 bf = *(const s16x8*)(w2bT + (long long)col * 256 + klane);
            #pragma unroll
            for (int mi = 0; mi < 2; ++mi)
                acc2[mi][nj] = __builtin_amdgcn_mfma_f32_16x16x32_bf16(af[mi], bf, acc2[mi][nj], 0, 0, 0);
        }
    }

    #pragma unroll
    for (int nj = 0; nj < 4; ++nj) {
        int col = wn * 64 + nj * 16 + (lane & 15);
        float bias = b2b[col];
        #pragma unroll
        for (int mi = 0; mi < 2; ++mi)
            #pragma unroll
            for (int rr = 0; rr < 4; ++rr) {
                int row = wm * 32 + mi * 16 + ((lane >> 4) << 2) + rr;
                int o = m0 + row;
                if (o < O) {
                    float v = acc2[mi][nj][rr] + bias;
                    v = v > 0.f ? v : 0.f;
                    outObj[(long long)o * 128 + col] = v;
                }
            }
    }
}

extern "C" void kernel_launch(void* const* d_in, const int* in_sizes, int n_in,
                              void* d_out, int out_size, void* d_ws, size_t ws_size,
                              hipStream_t stream) {
    const float* obj  = (const float*)d_in[0];
    const float* pred = (const float*)d_in[1];
    const int*   edges = (const int*)d_in[2];
    const float* w1a = (const float*)d_in[3];
    const float* b1a = (const float*)d_in[4];
    const float* w1b = (const float*)d_in[5];
    const float* b1b = (const float*)d_in[6];
    const float* w2a = (const float*)d_in[7];
    const float* b2a = (const float*)d_in[8];
    const float* w2b = (const float*)d_in[9];
    const float* b2b = (const float*)d_in[10];

    const int O = in_sizes[0] / 128;
    const int T = in_sizes[1] / 128;

    auto al = [](size_t x) { return (x + 255) & ~(size_t)255; };
    const size_t szEdgeout = (size_t)2 * T * 256 * 2;
    const size_t szPooled  = (size_t)O * 256 * 2;
    const size_t szCnt     = (size_t)O * 4;
    const size_t szRow     = (size_t)(O + 1) * 4;
    const size_t szSlot    = (size_t)T * 4;

    size_t off = 0;
    char* ws = (char*)d_ws;
    unsigned short* edgeout = (unsigned short*)(ws + off); off += al(szEdgeout);
    unsigned short* pooled  = (unsigned short*)(ws + off); off += al(szPooled);
    int* cnt    = (int*)(ws + off); off += al(szCnt);
    int* cursor = (int*)(ws + off); off += al(szCnt);
    int* rowptr = (int*)(ws + off); off += al(szRow);
    int* slotS  = (int*)(ws + off); off += al(szSlot);
    int* slotO  = (int*)(ws + off); off += al(szSlot);
    unsigned short* w1aT = (unsigned short*)(ws + off); off += (size_t)6 * 16384 * 2;
    unsigned short* w1bT = (unsigned short*)(ws + off); off += (size_t)10 * 16384 * 2;
    unsigned short* w2aT = (unsigned short*)(ws + off); off += (size_t)256 * 256 * 2;
    unsigned short* w2bT = (unsigned short*)(ws + off);

    float* outObj = (float*)d_out;
    float* outP   = (float*)d_out + (size_t)O * 128;

    hipMemsetAsync(cnt, 0, szCnt, stream);
    const int prepElems = 98304 + 163840 + 65536 + 32768;
    prep_weights<<<(prepElems + 255) / 256, 256, 0, stream>>>(w1a, w1b, w2a, w2b, w1aT, w1bT, w2aT, w2bT);
    count_kernel_i<<<(T + 255) / 256, 256, 0, stream>>>(edges, cnt, T);
    scan_kernel<<<1, 1024, 0, stream>>>(cnt, rowptr, cursor, O);
    slot_kernel<<<(T + 255) / 256, 256, 0, stream>>>(edges, cursor, slotS, slotO, T);
    edge_mlp<<<(T + 127) / 128, 512, 0, stream>>>(obj, pred, edges, w1aT, b1a, w1bT, b1b, slotS, slotO, edgeout, outP, T);
    pool_gather<<<(O + 3) / 4, 256, 0, stream>>>(edgeout, rowptr, pooled, O);
    obj_mlp<<<(O + 63) / 64, 256, 0, stream>>>(pooled, w2aT, b2a, w2bT, b2b, outObj, O);
}

// Round 14
// 901.753 us; speedup vs baseline: 2.1085x; 1.0170x over previous
//
#include <hip/hip_runtime.h>

// GraphConv: edge MLP (384->256->640, bf16 MFMA) + slot-direct CSR pool + obj MLP (256->256->128)
// Round 14: tail consolidation. (a) count+slot merged (local slot via one atomicAdd; atomic-free
// fixup adds rowptr) -> half the CSR atomics, one fewer pass. (b) pool_gather fused into
// obj_mlp's staging (gather contiguous CSR ranges straight to LDS) -> pooled buffer deleted.
// edge_mlp is BYTE-IDENTICAL to round 13 (control for attribution).

using f32x4 = __attribute__((ext_vector_type(4))) float;
using s16x8 = __attribute__((ext_vector_type(8))) short;
typedef unsigned short u16x8 __attribute__((ext_vector_type(8)));

#define VMCNT4  asm volatile("s_waitcnt vmcnt(4)" ::: "memory")
#define VMCNT8  asm volatile("s_waitcnt vmcnt(8)" ::: "memory")
#define VMCNT16 asm volatile("s_waitcnt vmcnt(16)" ::: "memory")
#define VMCNT20 asm volatile("s_waitcnt vmcnt(20)" ::: "memory")
#define VMCNT36 asm volatile("s_waitcnt vmcnt(36)" ::: "memory")
#define LGKM0   asm volatile("s_waitcnt lgkmcnt(0)" ::: "memory")
#define BAR     __builtin_amdgcn_s_barrier()
#define SCHEDB  __builtin_amdgcn_sched_barrier(0)

static __device__ __forceinline__ unsigned short f2b(float f) {
    unsigned int u = __float_as_uint(f);
    unsigned int r = (u + 0x7fffu + ((u >> 16) & 1u)) >> 16;  // RNE f32->bf16
    return (unsigned short)r;
}

static __device__ __forceinline__ float b2f(unsigned short b) {
    return __uint_as_float(((unsigned)b) << 16);
}

static __device__ __forceinline__ unsigned swz(unsigned row, unsigned byteoff) {
    return byteoff ^ ((row & 7u) << 4);
}

static __device__ __forceinline__ void gload_lds16(const unsigned short* g, unsigned short* l) {
    __builtin_amdgcn_global_load_lds(
        (const __attribute__((address_space(1))) unsigned int*)g,
        (__attribute__((address_space(3))) unsigned int*)l,
        16, 0, 0);
}

// ---------------- weight prep (identical to rounds 9-13) ----------------
__global__ void prep_weights(const float* __restrict__ w1a, const float* __restrict__ w1b,
                             const float* __restrict__ w2a, const float* __restrict__ w2b,
                             unsigned short* __restrict__ w1aT, unsigned short* __restrict__ w1bT,
                             unsigned short* __restrict__ w2aT, unsigned short* __restrict__ w2bT) {
    int t = blockIdx.x * blockDim.x + threadIdx.x;
    if (t < 6 * 16384) {
        int kt = t >> 14;
        int rem = t & 16383; int c = rem >> 6, kk = rem & 63;
        unsigned byte = ((unsigned)(c * 128 + kk * 2)) ^ ((c & 7u) << 4);
        *(unsigned short*)((char*)w1aT + (size_t)kt * 32768 + byte) =
            f2b(w1a[(size_t)(kt * 64 + kk) * 256 + c]);
        return;
    }
    t -= 98304;
    if (t < 10 * 16384) {
        int tile = t >> 14; int nc = tile >> 1, kh = tile & 1;
        int rem = t & 16383; int c = rem >> 7, kk = rem & 127;
        unsigned byte = ((unsigned)(c * 256 + kk * 2)) ^ ((c & 7u) << 4);
        *(unsigned short*)((char*)w1bT + (size_t)tile * 32768 + byte) =
            f2b(w1b[(size_t)(kh * 128 + kk) * 640 + nc * 128 + c]);
        return;
    }
    t -= 163840;
    if (t < 65536) { int n = t >> 8, k = t & 255; w2aT[t] = f2b(w2a[k * 256 + n]); return; }
    t -= 65536;
    if (t < 32768) { int n = t >> 8, k = t & 255; w2bT[t] = f2b(w2b[k * 128 + n]); return; }
}

// ---------------- CSR build: merged count+slot, scan, atomic-free fixup ----------------
__global__ void count_slot_kernel(const int* __restrict__ edges, int* __restrict__ cnt,
                                  int* __restrict__ slotS, int* __restrict__ slotO, int T) {
    int e = blockIdx.x * blockDim.x + threadIdx.x;
    if (e < T) {
        slotS[e] = atomicAdd(&cnt[edges[2 * (long long)e]], 1);
        slotO[e] = atomicAdd(&cnt[edges[2 * (long long)e + 1]], 1);
    }
}

__global__ void scan_kernel(const int* __restrict__ cnt, int* __restrict__ rowptr, int O) {
    __shared__ int sc[1024];
    const int tid = threadIdx.x;
    const int per = (O + 1023) >> 10;
    const int base = tid * per;
    int s = 0;
    for (int i = 0; i < per; ++i) { int j = base + i; if (j < O) s += cnt[j]; }
    sc[tid] = s;
    __syncthreads();
    for (int d = 1; d < 1024; d <<= 1) {
        int v = (tid >= d) ? sc[tid - d] : 0;
        __syncthreads();
        sc[tid] += v;
        __syncthreads();
    }
    int off = sc[tid] - s;
    for (int i = 0; i < per; ++i) {
        int j = base + i;
        if (j < O) { rowptr[j] = off; off += cnt[j]; }
    }
    if (tid == 0) rowptr[O] = sc[1023];
}

__global__ void fixup_kernel(const int* __restrict__ edges, const int* __restrict__ rowptr,
                             int* __restrict__ slotS, int* __restrict__ slotO, int T) {
    int e = blockIdx.x * blockDim.x + threadIdx.x;
    if (e < T) {
        slotS[e] += rowptr[edges[2 * (long long)e]];
        slotO[e] += rowptr[edges[2 * (long long)e + 1]];
    }
}

// ---------------- edge MLP: BYTE-IDENTICAL to round 13 ----------------
__global__ __launch_bounds__(512, 2) void edge_mlp(
    const float* __restrict__ obj, const float* __restrict__ pred,
    const int* __restrict__ edges,
    const unsigned short* __restrict__ w1aT, const float* __restrict__ b1a,
    const unsigned short* __restrict__ w1bT, const float* __restrict__ b1b,
    const int* __restrict__ slotS, const int* __restrict__ slotO,
    unsigned short* __restrict__ edgeout, float* __restrict__ outP, int T) {
    const int m0 = blockIdx.x * 128;
    const int tid = threadIdx.x;
    const int lane = tid & 63, wid = tid >> 6;
    const int wm = wid >> 2, wn = wid & 3;
    const bool evenL = ((lane & 1) == 0);

    __shared__ unsigned short U[81920];
    char* const ldsb = (char*)U;
    char* const bbase = ldsb + 65536;

    bool okR[4][4];
    #pragma unroll
    for (int mi = 0; mi < 4; ++mi)
        #pragma unroll
        for (int rr = 0; rr < 4; ++rr)
            okR[mi][rr] = (m0 + wm * 64 + mi * 16 + ((lane >> 4) << 2) + rr) < T;

    int slotSr[4][2], slotOr[4][2];
    #pragma unroll
    for (int mi = 0; mi < 4; ++mi)
        #pragma unroll
        for (int k = 0; k < 2; ++k) {
            int rsel = evenL ? k : 2 + k;
            int e = m0 + wm * 64 + mi * 16 + ((lane >> 4) << 2) + rsel;
            if (e >= T) e = T - 1;
            slotSr[mi][k] = slotS[e];
            slotOr[mi][k] = slotO[e];
        }

    const int r = tid >> 2;
    const int q = tid & 3;
    int e_r = m0 + r; if (e_r >= T) e_r = T - 1;
    const int sIdx_r = edges[2 * (long long)e_r];
    const int oIdx_r = edges[2 * (long long)e_r + 1];

    float bias1[4], bias2[5][2];
    #pragma unroll
    for (int nj = 0; nj < 4; ++nj) bias1[nj] = b1a[wn * 64 + nj * 16 + (lane & 15)];
    #pragma unroll
    for (int nc = 0; nc < 5; ++nc)
        #pragma unroll
        for (int nj = 0; nj < 2; ++nj)
            bias2[nc][nj] = b1b[nc * 128 + wn * 32 + nj * 16 + (lane & 15)];

    auto aSrc = [&](int kt) -> const float4* {
        const float* s;
        if (kt < 2)      s = obj  + (long long)sIdx_r * 128 + kt * 64;
        else if (kt < 4) s = pred + (long long)e_r   * 128 + (kt - 2) * 64;
        else             s = obj  + (long long)oIdx_r * 128 + (kt - 4) * 64;
        return (const float4*)s;
    };

    auto tp = [&](int i) -> const unsigned short* {
        return (i < 6) ? (w1aT + (size_t)i * 16384) : (w1bT + (size_t)(i - 6) * 16384);
    };

    auto stage32 = [&](const unsigned short* gt, char* bb) {
        #pragma unroll
        for (int rr4 = 0; rr4 < 4; ++rr4) {
            unsigned off = wid * 4096u + rr4 * 1024u;
            gload_lds16((const unsigned short*)((const char*)gt + off + lane * 16u),
                        (unsigned short*)(bb + off));
        }
    };

    auto writeA = [&](const float4* ap, char* ab) {
        #pragma unroll
        for (int i = 0; i < 4; ++i) {
            float4 v = ap[i];
            ushort4 pk; pk.x = f2b(v.x); pk.y = f2b(v.y); pk.z = f2b(v.z); pk.w = f2b(v.w);
            unsigned byte = (r * 128u + q * 32u + i * 8u) ^ ((r & 7u) << 4);
            *(ushort4*)(ab + byte) = pk;
        }
    };

    f32x4 acc1[4][4];
    #pragma unroll
    for (int a = 0; a < 4; ++a)
        #pragma unroll
        for (int b = 0; b < 4; ++b) acc1[a][b] = f32x4{0.f, 0.f, 0.f, 0.f};

    auto mfma1 = [&](const char* ab, const char* bb) {
        #pragma unroll
        for (int ks = 0; ks < 2; ++ks) {
            const unsigned kk = ks * 32u + ((lane >> 4) << 3);
            s16x8 af[4];
            #pragma unroll
            for (int mi = 0; mi < 4; ++mi) {
                unsigned row = wm * 64u + mi * 16u + (lane & 15);
                af[mi] = *(const s16x8*)(ab + ((row * 128u + kk * 2u) ^ ((row & 7u) << 4)));
            }
            #pragma unroll
            for (int nj = 0; nj < 4; ++nj) {
                unsigned c = wn * 64u + nj * 16u + (lane & 15);
                s16x8 bf = *(const s16x8*)(bb + ((c * 128u + kk * 2u) ^ ((c & 7u) << 4)));
                #pragma unroll
                for (int mi = 0; mi < 4; ++mi)
                    acc1[mi][nj] = __builtin_amdgcn_mfma_f32_16x16x32_bf16(af[mi], bf, acc1[mi][nj], 0, 0, 0);
            }
        }
    };

    // ---- prologue ----
    float4 ap[4];
    {
        const float4* s4 = aSrc(0);
        #pragma unroll
        for (int i = 0; i < 4; ++i) ap[i] = s4[q * 4 + i];
    }
    writeA(ap, ldsb);
    stage32(tp(0), bbase);
    stage32(tp(1), bbase + 32768);
    {
        const float4* s4 = aSrc(1);
        #pragma unroll
        for (int i = 0; i < 4; ++i) ap[i] = s4[q * 4 + i];
    }
    VMCNT8;
    LGKM0; BAR; SCHEDB;

    // ---- GEMM1 stages s=0..5 ----
    #pragma unroll
    for (int s = 0; s < 6; ++s) {
        stage32(tp(s + 2), bbase + ((s + 2) % 3) * 32768);
        __builtin_amdgcn_s_setprio(1);
        mfma1(ldsb + (s & 1) * 16384, bbase + (s % 3) * 32768);
        __builtin_amdgcn_s_setprio(0);
        VMCNT4;
        if (s < 5) {
            writeA(ap, ldsb + ((s + 1) & 1) * 16384);
            if (s < 4) {
                const float4* s4 = aSrc(s + 2);
                #pragma unroll
                for (int i = 0; i < 4; ++i) ap[i] = s4[q * 4 + i];
            }
        }
        LGKM0; BAR; SCHEDB;
    }

    // ---- transition: H write ----
    #pragma unroll
    for (int nj = 0; nj < 4; ++nj) {
        unsigned col = wn * 64u + nj * 16u + (lane & 15);
        #pragma unroll
        for (int mi = 0; mi < 4; ++mi)
            #pragma unroll
            for (int rr = 0; rr < 4; ++rr) {
                unsigned row = wm * 64u + mi * 16u + ((lane >> 4) << 2) + rr;
                float v = acc1[mi][nj][rr] + bias1[nj];
                v = v > 0.f ? v : 0.f;
                *(unsigned short*)(ldsb + ((row * 512u + col * 2u) ^ ((row & 7u) << 4))) = f2b(v);
            }
    }
    LGKM0; BAR; SCHEDB;

    // ---- GEMM2 stages s=6..15 ----
    #pragma unroll
    for (int nc = 0; nc < 5; ++nc) {
        f32x4 acc2[4][2];
        #pragma unroll
        for (int a = 0; a < 4; ++a)
            #pragma unroll
            for (int b = 0; b < 2; ++b) acc2[a][b] = f32x4{0.f, 0.f, 0.f, 0.f};

        #pragma unroll
        for (int kh = 0; kh < 2; ++kh) {
            const int s = 6 + nc * 2 + kh;
            if (s + 2 <= 15) stage32(tp(s + 2), bbase + ((s + 2) % 3) * 32768);
            const char* bb = bbase + (s % 3) * 32768;
            __builtin_amdgcn_s_setprio(1);
            #pragma unroll
            for (int ks = 0; ks < 4; ++ks) {
                const unsigned kkB = ks * 32u + ((lane >> 4) << 3);
                const unsigned kkH = (kh * 128u) + kkB;
                s16x8 af[4];
                #pragma unroll
                for (int mi = 0; mi < 4; ++mi) {
                    unsigned row = wm * 64u + mi * 16u + (lane & 15);
                    af[mi] = *(const s16x8*)(ldsb + ((row * 512u + kkH * 2u) ^ ((row & 7u) << 4)));
                }
                #pragma unroll
                for (int nj = 0; nj < 2; ++nj) {
                    unsigned c = wn * 32u + nj * 16u + (lane & 15);
                    s16x8 bf = *(const s16x8*)(bb + ((c * 256u + kkB * 2u) ^ ((c & 7u) << 4)));
                    #pragma unroll
                    for (int mi = 0; mi < 4; ++mi)
                        acc2[mi][nj] = __builtin_amdgcn_mfma_f32_16x16x32_bf16(af[mi], bf, acc2[mi][nj], 0, 0, 0);
                }
            }
            __builtin_amdgcn_s_setprio(0);

            if (kh == 0) {
                if (s == 6)       { VMCNT4; }
                else if (s == 12) { VMCNT36; }
                else if (s == 14) { VMCNT16; }
                else              { VMCNT20; }
                LGKM0; BAR; SCHEDB;
            }
        }

        if (nc == 2) {
            #pragma unroll
            for (int nj = 0; nj < 2; ++nj) {
                int col = 2 * 128 + wn * 32 + nj * 16 + (lane & 15);
                #pragma unroll
                for (int mi = 0; mi < 4; ++mi)
                    #pragma unroll
                    for (int rr = 0; rr < 4; ++rr) {
                        int row = wm * 64 + mi * 16 + ((lane >> 4) << 2) + rr;
                        if (okR[mi][rr]) {
                            float v = acc2[mi][nj][rr] + bias2[2][nj];
                            v = v > 0.f ? v : 0.f;
                            outP[(long long)(m0 + row) * 128 + (col - 256)] = v;
                        }
                    }
            }
            VMCNT36;
            LGKM0; BAR; SCHEDB;
        } else {
            #pragma unroll
            for (int nj = 0; nj < 2; ++nj) {
                int col = nc * 128 + wn * 32 + nj * 16 + (lane & 15);
                int pc = (nc < 2) ? col : (col - 384);
                int pcb = (lane & 1) ? (pc - 1) : pc;
                #pragma unroll
                for (int mi = 0; mi < 4; ++mi) {
                    float vv[4];
                    #pragma unroll
                    for (int rr = 0; rr < 4; ++rr) {
                        float v = acc2[mi][nj][rr] + bias2[nc][nj];
                        vv[rr] = v > 0.f ? v : 0.f;
                    }
                    float nb0 = __shfl_xor(vv[0], 1);
                    float nb1 = __shfl_xor(vv[1], 1);
                    float nb2 = __shfl_xor(vv[2], 1);
                    float nb3 = __shfl_xor(vv[3], 1);
                    #pragma unroll
                    for (int k = 0; k < 2; ++k) {
                        float lo = evenL ? (k ? vv[1] : vv[0]) : (k ? nb3 : nb2);
                        float hi = evenL ? (k ? nb1 : nb0) : (k ? vv[3] : vv[2]);
                        int rsel = evenL ? k : 2 + k;
                        if (okR[mi][rsel]) {
                            int slot = (nc < 2) ? slotSr[mi][k] : slotOr[mi][k];
                            unsigned pk = ((unsigned)f2b(hi) << 16) | f2b(lo);
                            *(unsigned*)(edgeout + (size_t)slot * 256 + pcb) = pk;
                        }
                    }
                }
            }
            if (nc < 4) {
                VMCNT20;
                LGKM0; BAR; SCHEDB;
            }
        }
    }
}

// ---------------- object MLP with fused CSR-gather staging ----------------
__global__ __launch_bounds__(256, 2) void obj_mlp(
    const unsigned short* __restrict__ edgeout, const int* __restrict__ rowptr,
    const unsigned short* __restrict__ w2aT, const float* __restrict__ b2a,
    const unsigned short* __restrict__ w2bT, const float* __restrict__ b2b,
    float* __restrict__ outObj, int O) {
    const int m0 = blockIdx.x * 64;
    const int tid = threadIdx.x;
    const int lane = tid & 63, wid = tid >> 6;
    const int wm = wid >> 1, wn = wid & 1;

    __shared__ unsigned short Abuf[64 * 256];

    // ---- fused gather staging: one object per wave per iteration (16 iters) ----
    for (int it = 0; it < 16; ++it) {
        const int row = it * 4 + wid;     // 0..63
        const int oI = m0 + row;
        float ax = 0.f, ay = 0.f, az = 0.f, aw = 0.f;
        float bx = 0.f, by = 0.f, bz = 0.f, bw = 0.f;
        int n = 0;
        if (oI < O) {
            const int beg = rowptr[oI];
            n = rowptr[oI + 1] - beg;
            const unsigned short* base = edgeout + (size_t)beg * 256 + lane * 4;
            int i = 0;
            for (; i + 3 < n; i += 4) {
                ushort4 v0 = *(const ushort4*)(base + (size_t)(i    ) * 256);
                ushort4 v1 = *(const ushort4*)(base + (size_t)(i + 1) * 256);
                ushort4 v2 = *(const ushort4*)(base + (size_t)(i + 2) * 256);
                ushort4 v3 = *(const ushort4*)(base + (size_t)(i + 3) * 256);
                ax += b2f(v0.x); ay += b2f(v0.y); az += b2f(v0.z); aw += b2f(v0.w);
                bx += b2f(v1.x); by += b2f(v1.y); bz += b2f(v1.z); bw += b2f(v1.w);
                ax += b2f(v2.x); ay += b2f(v2.y); az += b2f(v2.z); aw += b2f(v2.w);
                bx += b2f(v3.x); by += b2f(v3.y); bz += b2f(v3.z); bw += b2f(v3.w);
            }
            for (; i < n; ++i) {
                ushort4 v0 = *(const ushort4*)(base + (size_t)i * 256);
                ax += b2f(v0.x); ay += b2f(v0.y); az += b2f(v0.z); aw += b2f(v0.w);
            }
        }
        float inv = 1.f / fmaxf((float)n, 1.f);
        ushort4 pk;
        pk.x = f2b((ax + bx) * inv); pk.y = f2b((ay + by) * inv);
        pk.z = f2b((az + bz) * inv); pk.w = f2b((aw + bw) * inv);
        unsigned byte = ((unsigned)row * 512u + (unsigned)lane * 8u) ^ (((unsigned)row & 7u) << 4);
        *(ushort4*)((char*)Abuf + byte) = pk;   // oI>=O -> zeros
    }
    __syncthreads();

    // ---- GEMM A: [64,256] x [256,256] ----
    f32x4 acc1[2][2][4];
    #pragma unroll
    for (int a = 0; a < 2; ++a)
        #pragma unroll
        for (int b = 0; b < 2; ++b)
            #pragma unroll
            for (int c = 0; c < 4; ++c) acc1[a][b][c] = f32x4{0.f, 0.f, 0.f, 0.f};
    #pragma unroll
    for (int ks = 0; ks < 8; ++ks) {
        const int klane = ks * 32 + ((lane >> 4) << 3);
        s16x8 af[2];
        #pragma unroll
        for (int mi = 0; mi < 2; ++mi) {
            int row = wm * 32 + mi * 16 + (lane & 15);
            af[mi] = *(const s16x8*)((const char*)Abuf + swz(row, row * 512u + klane * 2u));
        }
        #pragma unroll
        for (int nb = 0; nb < 2; ++nb)
            #pragma unroll
            for (int nj = 0; nj < 4; ++nj) {
                int col = nb * 128 + wn * 64 + nj * 16 + (lane & 15);
                s16x8 bf = *(const s16x8*)(w2aT + (long long)col * 256 + klane);
                #pragma unroll
                for (int mi = 0; mi < 2; ++mi)
                    acc1[nb][mi][nj] = __builtin_amdgcn_mfma_f32_16x16x32_bf16(af[mi], bf, acc1[nb][mi][nj], 0, 0, 0);
            }
    }
    __syncthreads();

    // ---- H = relu(acc1 + b2a) -> Abuf ----
    #pragma unroll
    for (int nb = 0; nb < 2; ++nb)
        #pragma unroll
        for (int nj = 0; nj < 4; ++nj) {
            int col = nb * 128 + wn * 64 + nj * 16 + (lane & 15);
            float bias = b2a[col];
            #pragma unroll
            for (int mi = 0; mi < 2; ++mi)
                #pragma unroll
                for (int rr = 0; rr < 4; ++rr) {
                    int row = wm * 32 + mi * 16 + ((lane >> 4) << 2) + rr;
                    float v = acc1[nb][mi][nj][rr] + bias;
                    v = v > 0.f ? v : 0.f;
                    *(unsigned short*)((char*)Abuf + swz(row, row * 512u + col * 2u)) = f2b(v);
                }
        }
    __syncthreads();

    // ---- GEMM B: [64,256] x [256,128] ----
    f32x4 acc2[2][4];
    #pragma unroll
    for (int b = 0; b < 2; ++b)
        #pragma unroll
        for (int c = 0; c < 4; ++c) acc2[b][c] = f32x4{0.f, 0.f, 0.f, 0.f};
    #pragma unroll
    for (int ks = 0; ks < 8; ++ks) {
        const int klane = ks * 32 + ((lane >> 4) << 3);
        s16x8 af[2];
        #pragma unroll
        for (int mi = 0; mi < 2; ++mi) {
            int row = wm * 32 + mi * 16 + (lane & 15);
            af[mi] = *(const s16x8*)((const char*)Abuf + swz(row, row * 512u + klane * 2u));
        }
        #pragma unroll
        for (int nj = 0; nj < 4; ++nj) {
            int col = wn * 64 + nj * 16 + (lane & 15);
            s16x8 bf = *(const s16x8*)(w2bT + (long long)col * 256 + klane);
            #pragma unroll
            for (int mi = 0; mi < 2; ++mi)
                acc2[mi][nj] = __builtin_amdgcn_mfma_f32_16x16x32_bf16(af[mi], bf, acc2[mi][nj], 0, 0, 0);
        }
    }

    #pragma unroll
    for (int nj = 0; nj < 4; ++nj) {
        int col = wn * 64 + nj * 16 + (lane & 15);
        float bias = b2b[col];
        #pragma unroll
        for (int mi = 0; mi < 2; ++mi)
            #pragma unroll
            for (int rr = 0; rr < 4; ++rr) {
                int row = wm * 32 + mi * 16 + ((lane >> 4) << 2) + rr;
                int o = m0 + row;
                if (o < O) {
                    float v = acc2[mi][nj][rr] + bias;
                    v = v > 0.f ? v : 0.f;
                    outObj[(long long)o * 128 + col] = v;
                }
            }
    }
}

extern "C" void kernel_launch(void* const* d_in, const int* in_sizes, int n_in,
                              void* d_out, int out_size, void* d_ws, size_t ws_size,
                              hipStream_t stream) {
    const float* obj  = (const float*)d_in[0];
    const float* pred = (const float*)d_in[1];
    const int*   edges = (const int*)d_in[2];
    const float* w1a = (const float*)d_in[3];
    const float* b1a = (const float*)d_in[4];
    const float* w1b = (const float*)d_in[5];
    const float* b1b = (const float*)d_in[6];
    const float* w2a = (const float*)d_in[7];
    const float* b2a = (const float*)d_in[8];
    const float* w2b = (const float*)d_in[9];
    const float* b2b = (const float*)d_in[10];

    const int O = in_sizes[0] / 128;
    const int T = in_sizes[1] / 128;

    auto al = [](size_t x) { return (x + 255) & ~(size_t)255; };
    const size_t szEdgeout = (size_t)2 * T * 256 * 2;
    const size_t szCnt     = (size_t)O * 4;
    const size_t szRow     = (size_t)(O + 1) * 4;
    const size_t szSlot    = (size_t)T * 4;

    size_t off = 0;
    char* ws = (char*)d_ws;
    unsigned short* edgeout = (unsigned short*)(ws + off); off += al(szEdgeout);
    int* cnt    = (int*)(ws + off); off += al(szCnt);
    int* rowptr = (int*)(ws + off); off += al(szRow);
    int* slotS  = (int*)(ws + off); off += al(szSlot);
    int* slotO  = (int*)(ws + off); off += al(szSlot);
    unsigned short* w1aT = (unsigned short*)(ws + off); off += (size_t)6 * 16384 * 2;
    unsigned short* w1bT = (unsigned short*)(ws + off); off += (size_t)10 * 16384 * 2;
    unsigned short* w2aT = (unsigned short*)(ws + off); off += (size_t)256 * 256 * 2;
    unsigned short* w2bT = (unsigned short*)(ws + off);

    float* outObj = (float*)d_out;
    float* outP   = (float*)d_out + (size_t)O * 128;

    hipMemsetAsync(cnt, 0, szCnt, stream);
    const int prepElems = 98304 + 163840 + 65536 + 32768;
    prep_weights<<<(prepElems + 255) / 256, 256, 0, stream>>>(w1a, w1b, w2a, w2b, w1aT, w1bT, w2aT, w2bT);
    count_slot_kernel<<<(T + 255) / 256, 256, 0, stream>>>(edges, cnt, slotS, slotO, T);
    scan_kernel<<<1, 1024, 0, stream>>>(cnt, rowptr, O);
    fixup_kernel<<<(T + 255) / 256, 256, 0, stream>>>(edges, rowptr, slotS, slotO, T);
    edge_mlp<<<(T + 127) / 128, 512, 0, stream>>>(obj, pred, edges, w1aT, b1a, w1bT, b1b, slotS, slotO, edgeout, outP, T);
    obj_mlp<<<(O + 63) / 64, 256, 0, stream>>>(edgeout, rowptr, w2aT, b2a, w2bT, b2b, outObj, O);
}

// Round 15
// 893.696 us; speedup vs baseline: 2.1275x; 1.0090x over previous
//
#include <hip/hip_runtime.h>

// GraphConv: edge MLP (384->256->640, bf16 MFMA) + slot-direct CSR pool + obj MLP (256->256->128)
// Round 15: tail finish. (a) fixup kernel deleted: edge_mlp computes slot = local + rowptr[idx]
// in preamble, with empty-asm keep-alives force-retiring ALL preamble vmem loads before the
// prologue (clean vmcnt FIFO for the counted schedule). (b) count_slot merged into prep kernel.
// (c) obj_mlp gather 8-deep ILP + 3 blocks/CU. edge_mlp pipeline/table logic unchanged from r13.

using f32x4 = __attribute__((ext_vector_type(4))) float;
using s16x8 = __attribute__((ext_vector_type(8))) short;
typedef unsigned short u16x8 __attribute__((ext_vector_type(8)));

#define VMCNT4  asm volatile("s_waitcnt vmcnt(4)" ::: "memory")
#define VMCNT8  asm volatile("s_waitcnt vmcnt(8)" ::: "memory")
#define VMCNT16 asm volatile("s_waitcnt vmcnt(16)" ::: "memory")
#define VMCNT20 asm volatile("s_waitcnt vmcnt(20)" ::: "memory")
#define VMCNT36 asm volatile("s_waitcnt vmcnt(36)" ::: "memory")
#define LGKM0   asm volatile("s_waitcnt lgkmcnt(0)" ::: "memory")
#define BAR     __builtin_amdgcn_s_barrier()
#define SCHEDB  __builtin_amdgcn_sched_barrier(0)

static __device__ __forceinline__ unsigned short f2b(float f) {
    unsigned int u = __float_as_uint(f);
    unsigned int r = (u + 0x7fffu + ((u >> 16) & 1u)) >> 16;  // RNE f32->bf16
    return (unsigned short)r;
}

static __device__ __forceinline__ float b2f(unsigned short b) {
    return __uint_as_float(((unsigned)b) << 16);
}

static __device__ __forceinline__ unsigned swz(unsigned row, unsigned byteoff) {
    return byteoff ^ ((row & 7u) << 4);
}

static __device__ __forceinline__ void gload_lds16(const unsigned short* g, unsigned short* l) {
    __builtin_amdgcn_global_load_lds(
        (const __attribute__((address_space(1))) unsigned int*)g,
        (__attribute__((address_space(3))) unsigned int*)l,
        16, 0, 0);
}

#define PREP_ELEMS (98304 + 163840 + 65536 + 32768)   // 360448

// ---------------- fused weight prep + CSR count/slot ----------------
__global__ void prep_count_kernel(const float* __restrict__ w1a, const float* __restrict__ w1b,
                                  const float* __restrict__ w2a, const float* __restrict__ w2b,
                                  unsigned short* __restrict__ w1aT, unsigned short* __restrict__ w1bT,
                                  unsigned short* __restrict__ w2aT, unsigned short* __restrict__ w2bT,
                                  const int* __restrict__ edges, int* __restrict__ cnt,
                                  int* __restrict__ slotS, int* __restrict__ slotO, int T) {
    int t = blockIdx.x * blockDim.x + threadIdx.x;
    if (t >= PREP_ELEMS) {
        int e = t - PREP_ELEMS;
        if (e < T) {
            slotS[e] = atomicAdd(&cnt[edges[2 * (long long)e]], 1);
            slotO[e] = atomicAdd(&cnt[edges[2 * (long long)e + 1]], 1);
        }
        return;
    }
    if (t < 6 * 16384) {
        int kt = t >> 14;
        int rem = t & 16383; int c = rem >> 6, kk = rem & 63;
        unsigned byte = ((unsigned)(c * 128 + kk * 2)) ^ ((c & 7u) << 4);
        *(unsigned short*)((char*)w1aT + (size_t)kt * 32768 + byte) =
            f2b(w1a[(size_t)(kt * 64 + kk) * 256 + c]);
        return;
    }
    t -= 98304;
    if (t < 10 * 16384) {
        int tile = t >> 14; int nc = tile >> 1, kh = tile & 1;
        int rem = t & 16383; int c = rem >> 7, kk = rem & 127;
        unsigned byte = ((unsigned)(c * 256 + kk * 2)) ^ ((c & 7u) << 4);
        *(unsigned short*)((char*)w1bT + (size_t)tile * 32768 + byte) =
            f2b(w1b[(size_t)(kh * 128 + kk) * 640 + nc * 128 + c]);
        return;
    }
    t -= 163840;
    if (t < 65536) { int n = t >> 8, k = t & 255; w2aT[t] = f2b(w2a[k * 256 + n]); return; }
    t -= 65536;
    if (t < 32768) { int n = t >> 8, k = t & 255; w2bT[t] = f2b(w2b[k * 128 + n]); return; }
}

__global__ void scan_kernel(const int* __restrict__ cnt, int* __restrict__ rowptr, int O) {
    __shared__ int sc[1024];
    const int tid = threadIdx.x;
    const int per = (O + 1023) >> 10;
    const int base = tid * per;
    int s = 0;
    for (int i = 0; i < per; ++i) { int j = base + i; if (j < O) s += cnt[j]; }
    sc[tid] = s;
    __syncthreads();
    for (int d = 1; d < 1024; d <<= 1) {
        int v = (tid >= d) ? sc[tid - d] : 0;
        __syncthreads();
        sc[tid] += v;
        __syncthreads();
    }
    int off = sc[tid] - s;
    for (int i = 0; i < per; ++i) {
        int j = base + i;
        if (j < O) { rowptr[j] = off; off += cnt[j]; }
    }
    if (tid == 0) rowptr[O] = sc[1023];
}

// ---------------- edge MLP (r13 pipeline; fixup folded into preamble) ----------------
__global__ __launch_bounds__(512, 2) void edge_mlp(
    const float* __restrict__ obj, const float* __restrict__ pred,
    const int* __restrict__ edges,
    const unsigned short* __restrict__ w1aT, const float* __restrict__ b1a,
    const unsigned short* __restrict__ w1bT, const float* __restrict__ b1b,
    const int* __restrict__ slotS, const int* __restrict__ slotO,
    const int* __restrict__ rowptr,
    unsigned short* __restrict__ edgeout, float* __restrict__ outP, int T) {
    const int m0 = blockIdx.x * 128;
    const int tid = threadIdx.x;
    const int lane = tid & 63, wid = tid >> 6;
    const int wm = wid >> 2, wn = wid & 3;
    const bool evenL = ((lane & 1) == 0);

    __shared__ unsigned short U[81920];
    char* const ldsb = (char*)U;
    char* const bbase = ldsb + 65536;

    bool okR[4][4];
    #pragma unroll
    for (int mi = 0; mi < 4; ++mi)
        #pragma unroll
        for (int rr = 0; rr < 4; ++rr)
            okR[mi][rr] = (m0 + wm * 64 + mi * 16 + ((lane >> 4) << 2) + rr) < T;

    // global CSR slots = local slot + rowptr[node]  (fixup folded here)
    int slotSr[4][2], slotOr[4][2];
    #pragma unroll
    for (int mi = 0; mi < 4; ++mi)
        #pragma unroll
        for (int k = 0; k < 2; ++k) {
            int rsel = evenL ? k : 2 + k;
            int e = m0 + wm * 64 + mi * 16 + ((lane >> 4) << 2) + rsel;
            if (e >= T) e = T - 1;
            int si = edges[2 * (long long)e];
            int oi = edges[2 * (long long)e + 1];
            slotSr[mi][k] = slotS[e] + rowptr[si];
            slotOr[mi][k] = slotO[e] + rowptr[oi];
        }

    const int r = tid >> 2;
    const int q = tid & 3;
    int e_r = m0 + r; if (e_r >= T) e_r = T - 1;
    const int sIdx_r = edges[2 * (long long)e_r];
    const int oIdx_r = edges[2 * (long long)e_r + 1];

    float bias1[4], bias2[5][2];
    #pragma unroll
    for (int nj = 0; nj < 4; ++nj) bias1[nj] = b1a[wn * 64 + nj * 16 + (lane & 15)];
    #pragma unroll
    for (int nc = 0; nc < 5; ++nc)
        #pragma unroll
        for (int nj = 0; nj < 2; ++nj)
            bias2[nc][nj] = b1b[nc * 128 + wn * 32 + nj * 16 + (lane & 15)];

    // force-retire ALL preamble vmem loads: clean vmcnt FIFO before the counted pipeline
    #pragma unroll
    for (int mi = 0; mi < 4; ++mi)
        #pragma unroll
        for (int k = 0; k < 2; ++k)
            asm volatile("" :: "v"(slotSr[mi][k]), "v"(slotOr[mi][k]));
    #pragma unroll
    for (int nj = 0; nj < 4; ++nj) asm volatile("" :: "v"(bias1[nj]));
    #pragma unroll
    for (int nc = 0; nc < 5; ++nc)
        #pragma unroll
        for (int nj = 0; nj < 2; ++nj) asm volatile("" :: "v"(bias2[nc][nj]));
    asm volatile("" :: "v"((float)sIdx_r), "v"((float)oIdx_r));
    SCHEDB;

    auto aSrc = [&](int kt) -> const float4* {
        const float* s;
        if (kt < 2)      s = obj  + (long long)sIdx_r * 128 + kt * 64;
        else if (kt < 4) s = pred + (long long)e_r   * 128 + (kt - 2) * 64;
        else             s = obj  + (long long)oIdx_r * 128 + (kt - 4) * 64;
        return (const float4*)s;
    };

    auto tp = [&](int i) -> const unsigned short* {
        return (i < 6) ? (w1aT + (size_t)i * 16384) : (w1bT + (size_t)(i - 6) * 16384);
    };

    auto stage32 = [&](const unsigned short* gt, char* bb) {
        #pragma unroll
        for (int rr4 = 0; rr4 < 4; ++rr4) {
            unsigned off = wid * 4096u + rr4 * 1024u;
            gload_lds16((const unsigned short*)((const char*)gt + off + lane * 16u),
                        (unsigned short*)(bb + off));
        }
    };

    auto writeA = [&](const float4* ap, char* ab) {
        #pragma unroll
        for (int i = 0; i < 4; ++i) {
            float4 v = ap[i];
            ushort4 pk; pk.x = f2b(v.x); pk.y = f2b(v.y); pk.z = f2b(v.z); pk.w = f2b(v.w);
            unsigned byte = (r * 128u + q * 32u + i * 8u) ^ ((r & 7u) << 4);
            *(ushort4*)(ab + byte) = pk;
        }
    };

    f32x4 acc1[4][4];
    #pragma unroll
    for (int a = 0; a < 4; ++a)
        #pragma unroll
        for (int b = 0; b < 4; ++b) acc1[a][b] = f32x4{0.f, 0.f, 0.f, 0.f};

    auto mfma1 = [&](const char* ab, const char* bb) {
        #pragma unroll
        for (int ks = 0; ks < 2; ++ks) {
            const unsigned kk = ks * 32u + ((lane >> 4) << 3);
            s16x8 af[4];
            #pragma unroll
            for (int mi = 0; mi < 4; ++mi) {
                unsigned row = wm * 64u + mi * 16u + (lane & 15);
                af[mi] = *(const s16x8*)(ab + ((row * 128u + kk * 2u) ^ ((row & 7u) << 4)));
            }
            #pragma unroll
            for (int nj = 0; nj < 4; ++nj) {
                unsigned c = wn * 64u + nj * 16u + (lane & 15);
                s16x8 bf = *(const s16x8*)(bb + ((c * 128u + kk * 2u) ^ ((c & 7u) << 4)));
                #pragma unroll
                for (int mi = 0; mi < 4; ++mi)
                    acc1[mi][nj] = __builtin_amdgcn_mfma_f32_16x16x32_bf16(af[mi], bf, acc1[mi][nj], 0, 0, 0);
            }
        }
    };

    // ---- prologue ----
    float4 ap[4];
    {
        const float4* s4 = aSrc(0);
        #pragma unroll
        for (int i = 0; i < 4; ++i) ap[i] = s4[q * 4 + i];
    }
    writeA(ap, ldsb);
    stage32(tp(0), bbase);
    stage32(tp(1), bbase + 32768);
    {
        const float4* s4 = aSrc(1);
        #pragma unroll
        for (int i = 0; i < 4; ++i) ap[i] = s4[q * 4 + i];
    }
    VMCNT8;
    LGKM0; BAR; SCHEDB;

    // ---- GEMM1 stages s=0..5 ----
    #pragma unroll
    for (int s = 0; s < 6; ++s) {
        stage32(tp(s + 2), bbase + ((s + 2) % 3) * 32768);
        __builtin_amdgcn_s_setprio(1);
        mfma1(ldsb + (s & 1) * 16384, bbase + (s % 3) * 32768);
        __builtin_amdgcn_s_setprio(0);
        VMCNT4;
        if (s < 5) {
            writeA(ap, ldsb + ((s + 1) & 1) * 16384);
            if (s < 4) {
                const float4* s4 = aSrc(s + 2);
                #pragma unroll
                for (int i = 0; i < 4; ++i) ap[i] = s4[q * 4 + i];
            }
        }
        LGKM0; BAR; SCHEDB;
    }

    // ---- transition: H write ----
    #pragma unroll
    for (int nj = 0; nj < 4; ++nj) {
        unsigned col = wn * 64u + nj * 16u + (lane & 15);
        #pragma unroll
        for (int mi = 0; mi < 4; ++mi)
            #pragma unroll
            for (int rr = 0; rr < 4; ++rr) {
                unsigned row = wm * 64u + mi * 16u + ((lane >> 4) << 2) + rr;
                float v = acc1[mi][nj][rr] + bias1[nj];
                v = v > 0.f ? v : 0.f;
                *(unsigned short*)(ldsb + ((row * 512u + col * 2u) ^ ((row & 7u) << 4))) = f2b(v);
            }
    }
    LGKM0; BAR; SCHEDB;

    // ---- GEMM2 stages s=6..15 ----
    #pragma unroll
    for (int nc = 0; nc < 5; ++nc) {
        f32x4 acc2[4][2];
        #pragma unroll
        for (int a = 0; a < 4; ++a)
            #pragma unroll
            for (int b = 0; b < 2; ++b) acc2[a][b] = f32x4{0.f, 0.f, 0.f, 0.f};

        #pragma unroll
        for (int kh = 0; kh < 2; ++kh) {
            const int s = 6 + nc * 2 + kh;
            if (s + 2 <= 15) stage32(tp(s + 2), bbase + ((s + 2) % 3) * 32768);
            const char* bb = bbase + (s % 3) * 32768;
            __builtin_amdgcn_s_setprio(1);
            #pragma unroll
            for (int ks = 0; ks < 4; ++ks) {
                const unsigned kkB = ks * 32u + ((lane >> 4) << 3);
                const unsigned kkH = (kh * 128u) + kkB;
                s16x8 af[4];
                #pragma unroll
                for (int mi = 0; mi < 4; ++mi) {
                    unsigned row = wm * 64u + mi * 16u + (lane & 15);
                    af[mi] = *(const s16x8*)(ldsb + ((row * 512u + kkH * 2u) ^ ((row & 7u) << 4)));
                }
                #pragma unroll
                for (int nj = 0; nj < 2; ++nj) {
                    unsigned c = wn * 32u + nj * 16u + (lane & 15);
                    s16x8 bf = *(const s16x8*)(bb + ((c * 256u + kkB * 2u) ^ ((c & 7u) << 4)));
                    #pragma unroll
                    for (int mi = 0; mi < 4; ++mi)
                        acc2[mi][nj] = __builtin_amdgcn_mfma_f32_16x16x32_bf16(af[mi], bf, acc2[mi][nj], 0, 0, 0);
                }
            }
            __builtin_amdgcn_s_setprio(0);

            if (kh == 0) {
                if (s == 6)       { VMCNT4; }
                else if (s == 12) { VMCNT36; }
                else if (s == 14) { VMCNT16; }
                else              { VMCNT20; }
                LGKM0; BAR; SCHEDB;
            }
        }

        if (nc == 2) {
            #pragma unroll
            for (int nj = 0; nj < 2; ++nj) {
                int col = 2 * 128 + wn * 32 + nj * 16 + (lane & 15);
                #pragma unroll
                for (int mi = 0; mi < 4; ++mi)
                    #pragma unroll
                    for (int rr = 0; rr < 4; ++rr) {
                        int row = wm * 64 + mi * 16 + ((lane >> 4) << 2) + rr;
                        if (okR[mi][rr]) {
                            float v = acc2[mi][nj][rr] + bias2[2][nj];
                            v = v > 0.f ? v : 0.f;
                            outP[(long long)(m0 + row) * 128 + (col - 256)] = v;
                        }
                    }
            }
            VMCNT36;
            LGKM0; BAR; SCHEDB;
        } else {
            #pragma unroll
            for (int nj = 0; nj < 2; ++nj) {
                int col = nc * 128 + wn * 32 + nj * 16 + (lane & 15);
                int pc = (nc < 2) ? col : (col - 384);
                int pcb = (lane & 1) ? (pc - 1) : pc;
                #pragma unroll
                for (int mi = 0; mi < 4; ++mi) {
                    float vv[4];
                    #pragma unroll
                    for (int rr = 0; rr < 4; ++rr) {
                        float v = acc2[mi][nj][rr] + bias2[nc][nj];
                        vv[rr] = v > 0.f ? v : 0.f;
                    }
                    float nb0 = __shfl_xor(vv[0], 1);
                    float nb1 = __shfl_xor(vv[1], 1);
                    float nb2 = __shfl_xor(vv[2], 1);
                    float nb3 = __shfl_xor(vv[3], 1);
                    #pragma unroll
                    for (int k = 0; k < 2; ++k) {
                        float lo = evenL ? (k ? vv[1] : vv[0]) : (k ? nb3 : nb2);
                        float hi = evenL ? (k ? nb1 : nb0) : (k ? vv[3] : vv[2]);
                        int rsel = evenL ? k : 2 + k;
                        if (okR[mi][rsel]) {
                            int slot = (nc < 2) ? slotSr[mi][k] : slotOr[mi][k];
                            unsigned pk = ((unsigned)f2b(hi) << 16) | f2b(lo);
                            *(unsigned*)(edgeout + (size_t)slot * 256 + pcb) = pk;
                        }
                    }
                }
            }
            if (nc < 4) {
                VMCNT20;
                LGKM0; BAR; SCHEDB;
            }
        }
    }
}

// ---------------- object MLP with fused CSR-gather staging (8-deep ILP) ----------------
__global__ __launch_bounds__(256, 3) void obj_mlp(
    const unsigned short* __restrict__ edgeout, const int* __restrict__ rowptr,
    const unsigned short* __restrict__ w2aT, const float* __restrict__ b2a,
    const unsigned short* __restrict__ w2bT, const float* __restrict__ b2b,
    float* __restrict__ outObj, int O) {
    const int m0 = blockIdx.x * 64;
    const int tid = threadIdx.x;
    const int lane = tid & 63, wid = tid >> 6;
    const int wm = wid >> 1, wn = wid & 1;

    __shared__ unsigned short Abuf[64 * 256];

    for (int it = 0; it < 16; ++it) {
        const int row = it * 4 + wid;
        const int oI = m0 + row;
        float ax = 0.f, ay = 0.f, az = 0.f, aw = 0.f;
        float bx = 0.f, by = 0.f, bz = 0.f, bw = 0.f;
        int n = 0;
        if (oI < O) {
            const int beg = rowptr[oI];
            n = rowptr[oI + 1] - beg;
            const unsigned short* base = edgeout + (size_t)beg * 256 + lane * 4;
            int i = 0;
            for (; i + 7 < n; i += 8) {
                ushort4 v0 = *(const ushort4*)(base + (size_t)(i    ) * 256);
                ushort4 v1 = *(const ushort4*)(base + (size_t)(i + 1) * 256);
                ushort4 v2 = *(const ushort4*)(base + (size_t)(i + 2) * 256);
                ushort4 v3 = *(const ushort4*)(base + (size_t)(i + 3) * 256);
                ushort4 v4 = *(const ushort4*)(base + (size_t)(i + 4) * 256);
                ushort4 v5 = *(const ushort4*)(base + (size_t)(i + 5) * 256);
                ushort4 v6 = *(const ushort4*)(base + (size_t)(i + 6) * 256);
                ushort4 v7 = *(const ushort4*)(base + (size_t)(i + 7) * 256);
                ax += b2f(v0.x); ay += b2f(v0.y); az += b2f(v0.z); aw += b2f(v0.w);
                bx += b2f(v1.x); by += b2f(v1.y); bz += b2f(v1.z); bw += b2f(v1.w);
                ax += b2f(v2.x); ay += b2f(v2.y); az += b2f(v2.z); aw += b2f(v2.w);
                bx += b2f(v3.x); by += b2f(v3.y); bz += b2f(v3.z); bw += b2f(v3.w);
                ax += b2f(v4.x); ay += b2f(v4.y); az += b2f(v4.z); aw += b2f(v4.w);
                bx += b2f(v5.x); by += b2f(v5.y); bz += b2f(v5.z); bw += b2f(v5.w);
                ax += b2f(v6.x); ay += b2f(v6.y); az += b2f(v6.z); aw += b2f(v6.w);
                bx += b2f(v7.x); by += b2f(v7.y); bz += b2f(v7.z); bw += b2f(v7.w);
            }
            for (; i < n; ++i) {
                ushort4 v0 = *(const ushort4*)(base + (size_t)i * 256);
                ax += b2f(v0.x); ay += b2f(v0.y); az += b2f(v0.z); aw += b2f(v0.w);
            }
        }
        float inv = 1.f / fmaxf((float)n, 1.f);
        ushort4 pk;
        pk.x = f2b((ax + bx) * inv); pk.y = f2b((ay + by) * inv);
        pk.z = f2b((az + bz) * inv); pk.w = f2b((aw + bw) * inv);
        unsigned byte = ((unsigned)row * 512u + (unsigned)lane * 8u) ^ (((unsigned)row & 7u) << 4);
        *(ushort4*)((char*)Abuf + byte) = pk;
    }
    __syncthreads();

    f32x4 acc1[2][2][4];
    #pragma unroll
    for (int a = 0; a < 2; ++a)
        #pragma unroll
        for (int b = 0; b < 2; ++b)
            #pragma unroll
            for (int c = 0; c < 4; ++c) acc1[a][b][c] = f32x4{0.f, 0.f, 0.f, 0.f};
    #pragma unroll
    for (int ks = 0; ks < 8; ++ks) {
        const int klane = ks * 32 + ((lane >> 4) << 3);
        s16x8 af[2];
        #pragma unroll
        for (int mi = 0; mi < 2; ++mi) {
            int row = wm * 32 + mi * 16 + (lane & 15);
            af[mi] = *(const s16x8*)((const char*)Abuf + swz(row, row * 512u + klane * 2u));
        }
        #pragma unroll
        for (int nb = 0; nb < 2; ++nb)
            #pragma unroll
            for (int nj = 0; nj < 4; ++nj) {
                int col = nb * 128 + wn * 64 + nj * 16 + (lane & 15);
                s16x8 bf = *(const s16x8*)(w2aT + (long long)col * 256 + klane);
                #pragma unroll
                for (int mi = 0; mi < 2; ++mi)
                    acc1[nb][mi][nj] = __builtin_amdgcn_mfma_f32_16x16x32_bf16(af[mi], bf, acc1[nb][mi][nj], 0, 0, 0);
            }
    }
    __syncthreads();

    #pragma unroll
    for (int nb = 0; nb < 2; ++nb)
        #pragma unroll
        for (int nj = 0; nj < 4; ++nj) {
            int col = nb * 128 + wn * 64 + nj * 16 + (lane & 15);
            float bias = b2a[col];
            #pragma unroll
            for (int mi = 0; mi < 2; ++mi)
                #pragma unroll
                for (int rr = 0; rr < 4; ++rr) {
                    int row = wm * 32 + mi * 16 + ((lane >> 4) << 2) + rr;
                    float v = acc1[nb][mi][nj][rr] + bias;
                    v = v > 0.f ? v : 0.f;
                    *(unsigned short*)((char*)Abuf + swz(row, row * 512u + col * 2u)) = f2b(v);
                }
        }
    __syncthreads();

    f32x4 acc2[2][4];
    #pragma unroll
    for (int b = 0; b < 2; ++b)
        #pragma unroll
        for (int c = 0; c < 4; ++c) acc2[b][c] = f32x4{0.f, 0.f, 0.f, 0.f};
    #pragma unroll
    for (int ks = 0; ks < 8; ++ks) {
        const int klane = ks * 32 + ((lane >> 4) << 3);
        s16x8 af[2];
        #pragma unroll
        for (int mi = 0; mi < 2; ++mi) {
            int row = wm * 32 + mi * 16 + (lane & 15);
            af[mi] = *(const s16x8*)((const char*)Abuf + swz(row, row * 512u + klane * 2u));
        }
        #pragma unroll
        for (int nj = 0; nj < 4; ++nj) {
            int col = wn * 64 + nj * 16 + (lane & 15);
            s16x8 bf = *(const s16x8*)(w2bT + (long long)col * 256 + klane);
            #pragma unroll
            for (int mi = 0; mi < 2; ++mi)
                acc2[mi][nj] = __builtin_amdgcn_mfma_f32_16x16x32_bf16(af[mi], bf, acc2[mi][nj], 0, 0, 0);
        }
    }

    #pragma unroll
    for (int nj = 0; nj < 4; ++nj) {
        int col = wn * 64 + nj * 16 + (lane & 15);
        float bias = b2b[col];
        #pragma unroll
        for (int mi = 0; mi < 2; ++mi)
            #pragma unroll
            for (int rr = 0; rr < 4; ++rr) {
                int row = wm * 32 + mi * 16 + ((lane >> 4) << 2) + rr;
                int o = m0 + row;
                if (o < O) {
                    float v = acc2[mi][nj][rr] + bias;
                    v = v > 0.f ? v : 0.f;
                    outObj[(long long)o * 128 + col] = v;
                }
            }
    }
}

extern "C" void kernel_launch(void* const* d_in, const int* in_sizes, int n_in,
                              void* d_out, int out_size, void* d_ws, size_t ws_size,
                              hipStream_t stream) {
    const float* obj  = (const float*)d_in[0];
    const float* pred = (const float*)d_in[1];
    const int*   edges = (const int*)d_in[2];
    const float* w1a = (const float*)d_in[3];
    const float* b1a = (const float*)d_in[4];
    const float* w1b = (const float*)d_in[5];
    const float* b1b = (const float*)d_in[6];
    const float* w2a = (const float*)d_in[7];
    const float* b2a = (const float*)d_in[8];
    const float* w2b = (const float*)d_in[9];
    const float* b2b = (const float*)d_in[10];

    const int O = in_sizes[0] / 128;
    const int T = in_sizes[1] / 128;

    auto al = [](size_t x) { return (x + 255) & ~(size_t)255; };
    const size_t szEdgeout = (size_t)2 * T * 256 * 2;
    const size_t szCnt     = (size_t)O * 4;
    const size_t szRow     = (size_t)(O + 1) * 4;
    const size_t szSlot    = (size_t)T * 4;

    size_t off = 0;
    char* ws = (char*)d_ws;
    unsigned short* edgeout = (unsigned short*)(ws + off); off += al(szEdgeout);
    int* cnt    = (int*)(ws + off); off += al(szCnt);
    int* rowptr = (int*)(ws + off); off += al(szRow);
    int* slotS  = (int*)(ws + off); off += al(szSlot);
    int* slotO  = (int*)(ws + off); off += al(szSlot);
    unsigned short* w1aT = (unsigned short*)(ws + off); off += (size_t)6 * 16384 * 2;
    unsigned short* w1bT = (unsigned short*)(ws + off); off += (size_t)10 * 16384 * 2;
    unsigned short* w2aT = (unsigned short*)(ws + off); off += (size_t)256 * 256 * 2;
    unsigned short* w2bT = (unsigned short*)(ws + off);

    float* outObj = (float*)d_out;
    float* outP   = (float*)d_out + (size_t)O * 128;

    hipMemsetAsync(cnt, 0, szCnt, stream);
    const int totalT = PREP_ELEMS + T;
    prep_count_kernel<<<(totalT + 255) / 256, 256, 0, stream>>>(
        w1a, w1b, w2a, w2b, w1aT, w1bT, w2aT, w2bT, edges, cnt, slotS, slotO, T);
    scan_kernel<<<1, 1024, 0, stream>>>(cnt, rowptr, O);
    edge_mlp<<<(T + 127) / 128, 512, 0, stream>>>(obj, pred, edges, w1aT, b1a, w1bT, b1b,
                                                  slotS, slotO, rowptr, edgeout, outP, T);
    obj_mlp<<<(O + 63) / 64, 256, 0, stream>>>(edgeout, rowptr, w2aT, b2a, w2bT, b2b, outObj, O);
}

// Round 16
// 880.507 us; speedup vs baseline: 2.1594x; 1.0150x over previous
//
#include <hip/hip_runtime.h>

// GraphConv: edge MLP (384->256->640, bf16 MFMA) + slot-direct CSR pool + obj MLP (256->256->128)
// Round 16: all paired f32->bf16 conversions use v_cvt_pk_bf16_f32 (1 op per pair vs ~8-9 for
// manual RNE bit-twiddling) — targets the measured 30% VALUBusy (f2b was ~45% of VALU ops).
// Pipeline, tiles, waits, and memory structure byte-identical to round 15.

using f32x4 = __attribute__((ext_vector_type(4))) float;
using s16x8 = __attribute__((ext_vector_type(8))) short;
typedef unsigned short u16x8 __attribute__((ext_vector_type(8)));

#define VMCNT4  asm volatile("s_waitcnt vmcnt(4)" ::: "memory")
#define VMCNT8  asm volatile("s_waitcnt vmcnt(8)" ::: "memory")
#define VMCNT16 asm volatile("s_waitcnt vmcnt(16)" ::: "memory")
#define VMCNT20 asm volatile("s_waitcnt vmcnt(20)" ::: "memory")
#define VMCNT36 asm volatile("s_waitcnt vmcnt(36)" ::: "memory")
#define LGKM0   asm volatile("s_waitcnt lgkmcnt(0)" ::: "memory")
#define BAR     __builtin_amdgcn_s_barrier()
#define SCHEDB  __builtin_amdgcn_sched_barrier(0)

static __device__ __forceinline__ unsigned short f2b(float f) {
    unsigned int u = __float_as_uint(f);
    unsigned int r = (u + 0x7fffu + ((u >> 16) & 1u)) >> 16;  // RNE f32->bf16 (unpaired sites)
    return (unsigned short)r;
}

// packed RNE f32x2 -> bf16x2 (lo = first arg, hi = second) — hardware cvt, 1 VALU op
static __device__ __forceinline__ unsigned f2bpk(float lo, float hi) {
    unsigned r;
    asm("v_cvt_pk_bf16_f32 %0, %1, %2" : "=v"(r) : "v"(lo), "v"(hi));
    return r;
}

static __device__ __forceinline__ float b2f(unsigned short b) {
    return __uint_as_float(((unsigned)b) << 16);
}

static __device__ __forceinline__ unsigned swz(unsigned row, unsigned byteoff) {
    return byteoff ^ ((row & 7u) << 4);
}

static __device__ __forceinline__ void gload_lds16(const unsigned short* g, unsigned short* l) {
    __builtin_amdgcn_global_load_lds(
        (const __attribute__((address_space(1))) unsigned int*)g,
        (__attribute__((address_space(3))) unsigned int*)l,
        16, 0, 0);
}

#define PREP_ELEMS (98304 + 163840 + 65536 + 32768)   // 360448

// ---------------- fused weight prep + CSR count/slot ----------------
__global__ void prep_count_kernel(const float* __restrict__ w1a, const float* __restrict__ w1b,
                                  const float* __restrict__ w2a, const float* __restrict__ w2b,
                                  unsigned short* __restrict__ w1aT, unsigned short* __restrict__ w1bT,
                                  unsigned short* __restrict__ w2aT, unsigned short* __restrict__ w2bT,
                                  const int* __restrict__ edges, int* __restrict__ cnt,
                                  int* __restrict__ slotS, int* __restrict__ slotO, int T) {
    int t = blockIdx.x * blockDim.x + threadIdx.x;
    if (t >= PREP_ELEMS) {
        int e = t - PREP_ELEMS;
        if (e < T) {
            slotS[e] = atomicAdd(&cnt[edges[2 * (long long)e]], 1);
            slotO[e] = atomicAdd(&cnt[edges[2 * (long long)e + 1]], 1);
        }
        return;
    }
    if (t < 6 * 16384) {
        int kt = t >> 14;
        int rem = t & 16383; int c = rem >> 6, kk = rem & 63;
        unsigned byte = ((unsigned)(c * 128 + kk * 2)) ^ ((c & 7u) << 4);
        *(unsigned short*)((char*)w1aT + (size_t)kt * 32768 + byte) =
            f2b(w1a[(size_t)(kt * 64 + kk) * 256 + c]);
        return;
    }
    t -= 98304;
    if (t < 10 * 16384) {
        int tile = t >> 14; int nc = tile >> 1, kh = tile & 1;
        int rem = t & 16383; int c = rem >> 7, kk = rem & 127;
        unsigned byte = ((unsigned)(c * 256 + kk * 2)) ^ ((c & 7u) << 4);
        *(unsigned short*)((char*)w1bT + (size_t)tile * 32768 + byte) =
            f2b(w1b[(size_t)(kh * 128 + kk) * 640 + nc * 128 + c]);
        return;
    }
    t -= 163840;
    if (t < 65536) { int n = t >> 8, k = t & 255; w2aT[t] = f2b(w2a[k * 256 + n]); return; }
    t -= 65536;
    if (t < 32768) { int n = t >> 8, k = t & 255; w2bT[t] = f2b(w2b[k * 128 + n]); return; }
}

__global__ void scan_kernel(const int* __restrict__ cnt, int* __restrict__ rowptr, int O) {
    __shared__ int sc[1024];
    const int tid = threadIdx.x;
    const int per = (O + 1023) >> 10;
    const int base = tid * per;
    int s = 0;
    for (int i = 0; i < per; ++i) { int j = base + i; if (j < O) s += cnt[j]; }
    sc[tid] = s;
    __syncthreads();
    for (int d = 1; d < 1024; d <<= 1) {
        int v = (tid >= d) ? sc[tid - d] : 0;
        __syncthreads();
        sc[tid] += v;
        __syncthreads();
    }
    int off = sc[tid] - s;
    for (int i = 0; i < per; ++i) {
        int j = base + i;
        if (j < O) { rowptr[j] = off; off += cnt[j]; }
    }
    if (tid == 0) rowptr[O] = sc[1023];
}

// ---------------- edge MLP (r15 pipeline; cvt_pk conversions) ----------------
__global__ __launch_bounds__(512, 2) void edge_mlp(
    const float* __restrict__ obj, const float* __restrict__ pred,
    const int* __restrict__ edges,
    const unsigned short* __restrict__ w1aT, const float* __restrict__ b1a,
    const unsigned short* __restrict__ w1bT, const float* __restrict__ b1b,
    const int* __restrict__ slotS, const int* __restrict__ slotO,
    const int* __restrict__ rowptr,
    unsigned short* __restrict__ edgeout, float* __restrict__ outP, int T) {
    const int m0 = blockIdx.x * 128;
    const int tid = threadIdx.x;
    const int lane = tid & 63, wid = tid >> 6;
    const int wm = wid >> 2, wn = wid & 3;
    const bool evenL = ((lane & 1) == 0);

    __shared__ unsigned short U[81920];
    char* const ldsb = (char*)U;
    char* const bbase = ldsb + 65536;

    bool okR[4][4];
    #pragma unroll
    for (int mi = 0; mi < 4; ++mi)
        #pragma unroll
        for (int rr = 0; rr < 4; ++rr)
            okR[mi][rr] = (m0 + wm * 64 + mi * 16 + ((lane >> 4) << 2) + rr) < T;

    // global CSR slots = local slot + rowptr[node]
    int slotSr[4][2], slotOr[4][2];
    #pragma unroll
    for (int mi = 0; mi < 4; ++mi)
        #pragma unroll
        for (int k = 0; k < 2; ++k) {
            int rsel = evenL ? k : 2 + k;
            int e = m0 + wm * 64 + mi * 16 + ((lane >> 4) << 2) + rsel;
            if (e >= T) e = T - 1;
            int si = edges[2 * (long long)e];
            int oi = edges[2 * (long long)e + 1];
            slotSr[mi][k] = slotS[e] + rowptr[si];
            slotOr[mi][k] = slotO[e] + rowptr[oi];
        }

    const int r = tid >> 2;
    const int q = tid & 3;
    int e_r = m0 + r; if (e_r >= T) e_r = T - 1;
    const int sIdx_r = edges[2 * (long long)e_r];
    const int oIdx_r = edges[2 * (long long)e_r + 1];

    float bias1[4], bias2[5][2];
    #pragma unroll
    for (int nj = 0; nj < 4; ++nj) bias1[nj] = b1a[wn * 64 + nj * 16 + (lane & 15)];
    #pragma unroll
    for (int nc = 0; nc < 5; ++nc)
        #pragma unroll
        for (int nj = 0; nj < 2; ++nj)
            bias2[nc][nj] = b1b[nc * 128 + wn * 32 + nj * 16 + (lane & 15)];

    // force-retire ALL preamble vmem loads: clean vmcnt FIFO before the counted pipeline
    #pragma unroll
    for (int mi = 0; mi < 4; ++mi)
        #pragma unroll
        for (int k = 0; k < 2; ++k)
            asm volatile("" :: "v"(slotSr[mi][k]), "v"(slotOr[mi][k]));
    #pragma unroll
    for (int nj = 0; nj < 4; ++nj) asm volatile("" :: "v"(bias1[nj]));
    #pragma unroll
    for (int nc = 0; nc < 5; ++nc)
        #pragma unroll
        for (int nj = 0; nj < 2; ++nj) asm volatile("" :: "v"(bias2[nc][nj]));
    asm volatile("" :: "v"((float)sIdx_r), "v"((float)oIdx_r));
    SCHEDB;

    auto aSrc = [&](int kt) -> const float4* {
        const float* s;
        if (kt < 2)      s = obj  + (long long)sIdx_r * 128 + kt * 64;
        else if (kt < 4) s = pred + (long long)e_r   * 128 + (kt - 2) * 64;
        else             s = obj  + (long long)oIdx_r * 128 + (kt - 4) * 64;
        return (const float4*)s;
    };

    auto tp = [&](int i) -> const unsigned short* {
        return (i < 6) ? (w1aT + (size_t)i * 16384) : (w1bT + (size_t)(i - 6) * 16384);
    };

    auto stage32 = [&](const unsigned short* gt, char* bb) {
        #pragma unroll
        for (int rr4 = 0; rr4 < 4; ++rr4) {
            unsigned off = wid * 4096u + rr4 * 1024u;
            gload_lds16((const unsigned short*)((const char*)gt + off + lane * 16u),
                        (unsigned short*)(bb + off));
        }
    };

    auto writeA = [&](const float4* ap, char* ab) {
        #pragma unroll
        for (int i = 0; i < 4; ++i) {
            float4 v = ap[i];
            uint2 pk;
            pk.x = f2bpk(v.x, v.y);
            pk.y = f2bpk(v.z, v.w);
            unsigned byte = (r * 128u + q * 32u + i * 8u) ^ ((r & 7u) << 4);
            *(uint2*)(ab + byte) = pk;
        }
    };

    f32x4 acc1[4][4];
    #pragma unroll
    for (int a = 0; a < 4; ++a)
        #pragma unroll
        for (int b = 0; b < 4; ++b) acc1[a][b] = f32x4{0.f, 0.f, 0.f, 0.f};

    auto mfma1 = [&](const char* ab, const char* bb) {
        #pragma unroll
        for (int ks = 0; ks < 2; ++ks) {
            const unsigned kk = ks * 32u + ((lane >> 4) << 3);
            s16x8 af[4];
            #pragma unroll
            for (int mi = 0; mi < 4; ++mi) {
                unsigned row = wm * 64u + mi * 16u + (lane & 15);
                af[mi] = *(const s16x8*)(ab + ((row * 128u + kk * 2u) ^ ((row & 7u) << 4)));
            }
            #pragma unroll
            for (int nj = 0; nj < 4; ++nj) {
                unsigned c = wn * 64u + nj * 16u + (lane & 15);
                s16x8 bf = *(const s16x8*)(bb + ((c * 128u + kk * 2u) ^ ((c & 7u) << 4)));
                #pragma unroll
                for (int mi = 0; mi < 4; ++mi)
                    acc1[mi][nj] = __builtin_amdgcn_mfma_f32_16x16x32_bf16(af[mi], bf, acc1[mi][nj], 0, 0, 0);
            }
        }
    };

    // ---- prologue ----
    float4 ap[4];
    {
        const float4* s4 = aSrc(0);
        #pragma unroll
        for (int i = 0; i < 4; ++i) ap[i] = s4[q * 4 + i];
    }
    writeA(ap, ldsb);
    stage32(tp(0), bbase);
    stage32(tp(1), bbase + 32768);
    {
        const float4* s4 = aSrc(1);
        #pragma unroll
        for (int i = 0; i < 4; ++i) ap[i] = s4[q * 4 + i];
    }
    VMCNT8;
    LGKM0; BAR; SCHEDB;

    // ---- GEMM1 stages s=0..5 ----
    #pragma unroll
    for (int s = 0; s < 6; ++s) {
        stage32(tp(s + 2), bbase + ((s + 2) % 3) * 32768);
        __builtin_amdgcn_s_setprio(1);
        mfma1(ldsb + (s & 1) * 16384, bbase + (s % 3) * 32768);
        __builtin_amdgcn_s_setprio(0);
        VMCNT4;
        if (s < 5) {
            writeA(ap, ldsb + ((s + 1) & 1) * 16384);
            if (s < 4) {
                const float4* s4 = aSrc(s + 2);
                #pragma unroll
                for (int i = 0; i < 4; ++i) ap[i] = s4[q * 4 + i];
            }
        }
        LGKM0; BAR; SCHEDB;
    }

    // ---- transition: H write (cvt_pk pairs over rr) ----
    #pragma unroll
    for (int nj = 0; nj < 4; ++nj) {
        unsigned col = wn * 64u + nj * 16u + (lane & 15);
        #pragma unroll
        for (int mi = 0; mi < 4; ++mi) {
            float r0 = fmaxf(acc1[mi][nj][0] + bias1[nj], 0.f);
            float r1 = fmaxf(acc1[mi][nj][1] + bias1[nj], 0.f);
            float r2 = fmaxf(acc1[mi][nj][2] + bias1[nj], 0.f);
            float r3 = fmaxf(acc1[mi][nj][3] + bias1[nj], 0.f);
            unsigned p01 = f2bpk(r0, r1);
            unsigned p23 = f2bpk(r2, r3);
            unsigned rowb = wm * 64u + mi * 16u + ((lane >> 4) << 2);
            *(unsigned short*)(ldsb + ((rowb * 512u + col * 2u) ^ ((rowb & 7u) << 4))) = (unsigned short)p01;
            *(unsigned short*)(ldsb + (((rowb + 1) * 512u + col * 2u) ^ (((rowb + 1) & 7u) << 4))) = (unsigned short)(p01 >> 16);
            *(unsigned short*)(ldsb + (((rowb + 2) * 512u + col * 2u) ^ (((rowb + 2) & 7u) << 4))) = (unsigned short)p23;
            *(unsigned short*)(ldsb + (((rowb + 3) * 512u + col * 2u) ^ (((rowb + 3) & 7u) << 4))) = (unsigned short)(p23 >> 16);
        }
    }
    LGKM0; BAR; SCHEDB;

    // ---- GEMM2 stages s=6..15 ----
    #pragma unroll
    for (int nc = 0; nc < 5; ++nc) {
        f32x4 acc2[4][2];
        #pragma unroll
        for (int a = 0; a < 4; ++a)
            #pragma unroll
            for (int b = 0; b < 2; ++b) acc2[a][b] = f32x4{0.f, 0.f, 0.f, 0.f};

        #pragma unroll
        for (int kh = 0; kh < 2; ++kh) {
            const int s = 6 + nc * 2 + kh;
            if (s + 2 <= 15) stage32(tp(s + 2), bbase + ((s + 2) % 3) * 32768);
            const char* bb = bbase + (s % 3) * 32768;
            __builtin_amdgcn_s_setprio(1);
            #pragma unroll
            for (int ks = 0; ks < 4; ++ks) {
                const unsigned kkB = ks * 32u + ((lane >> 4) << 3);
                const unsigned kkH = (kh * 128u) + kkB;
                s16x8 af[4];
                #pragma unroll
                for (int mi = 0; mi < 4; ++mi) {
                    unsigned row = wm * 64u + mi * 16u + (lane & 15);
                    af[mi] = *(const s16x8*)(ldsb + ((row * 512u + kkH * 2u) ^ ((row & 7u) << 4)));
                }
                #pragma unroll
                for (int nj = 0; nj < 2; ++nj) {
                    unsigned c = wn * 32u + nj * 16u + (lane & 15);
                    s16x8 bf = *(const s16x8*)(bb + ((c * 256u + kkB * 2u) ^ ((c & 7u) << 4)));
                    #pragma unroll
                    for (int mi = 0; mi < 4; ++mi)
                        acc2[mi][nj] = __builtin_amdgcn_mfma_f32_16x16x32_bf16(af[mi], bf, acc2[mi][nj], 0, 0, 0);
                }
            }
            __builtin_amdgcn_s_setprio(0);

            if (kh == 0) {
                if (s == 6)       { VMCNT4; }
                else if (s == 12) { VMCNT36; }
                else if (s == 14) { VMCNT16; }
                else              { VMCNT20; }
                LGKM0; BAR; SCHEDB;
            }
        }

        if (nc == 2) {
            #pragma unroll
            for (int nj = 0; nj < 2; ++nj) {
                int col = 2 * 128 + wn * 32 + nj * 16 + (lane & 15);
                #pragma unroll
                for (int mi = 0; mi < 4; ++mi)
                    #pragma unroll
                    for (int rr = 0; rr < 4; ++rr) {
                        int row = wm * 64 + mi * 16 + ((lane >> 4) << 2) + rr;
                        if (okR[mi][rr]) {
                            float v = acc2[mi][nj][rr] + bias2[2][nj];
                            v = v > 0.f ? v : 0.f;
                            outP[(long long)(m0 + row) * 128 + (col - 256)] = v;
                        }
                    }
            }
            VMCNT36;
            LGKM0; BAR; SCHEDB;
        } else {
            #pragma unroll
            for (int nj = 0; nj < 2; ++nj) {
                int col = nc * 128 + wn * 32 + nj * 16 + (lane & 15);
                int pc = (nc < 2) ? col : (col - 384);
                int pcb = (lane & 1) ? (pc - 1) : pc;
                #pragma unroll
                for (int mi = 0; mi < 4; ++mi) {
                    float vv[4];
                    #pragma unroll
                    for (int rr = 0; rr < 4; ++rr) {
                        float v = acc2[mi][nj][rr] + bias2[nc][nj];
                        vv[rr] = v > 0.f ? v : 0.f;
                    }
                    float nb0 = __shfl_xor(vv[0], 1);
                    float nb1 = __shfl_xor(vv[1], 1);
                    float nb2 = __shfl_xor(vv[2], 1);
                    float nb3 = __shfl_xor(vv[3], 1);
                    #pragma unroll
                    for (int k = 0; k < 2; ++k) {
                        float lo = evenL ? (k ? vv[1] : vv[0]) : (k ? nb3 : nb2);
                        float hi = evenL ? (k ? nb1 : nb0) : (k ? vv[3] : vv[2]);
                        int rsel = evenL ? k : 2 + k;
                        if (okR[mi][rsel]) {
                            int slot = (nc < 2) ? slotSr[mi][k] : slotOr[mi][k];
                            unsigned pk = f2bpk(lo, hi);
                            *(unsigned*)(edgeout + (size_t)slot * 256 + pcb) = pk;
                        }
                    }
                }
            }
            if (nc < 4) {
                VMCNT20;
                LGKM0; BAR; SCHEDB;
            }
        }
    }
}

// ---------------- object MLP with fused CSR-gather staging ----------------
__global__ __launch_bounds__(256, 3) void obj_mlp(
    const unsigned short* __restrict__ edgeout, const int* __restrict__ rowptr,
    const unsigned short* __restrict__ w2aT, const float* __restrict__ b2a,
    const unsigned short* __restrict__ w2bT, const float* __restrict__ b2b,
    float* __restrict__ outObj, int O) {
    const int m0 = blockIdx.x * 64;
    const int tid = threadIdx.x;
    const int lane = tid & 63, wid = tid >> 6;
    const int wm = wid >> 1, wn = wid & 1;

    __shared__ unsigned short Abuf[64 * 256];

    for (int it = 0; it < 16; ++it) {
        const int row = it * 4 + wid;
        const int oI = m0 + row;
        float ax = 0.f, ay = 0.f, az = 0.f, aw = 0.f;
        float bx = 0.f, by = 0.f, bz = 0.f, bw = 0.f;
        int n = 0;
        if (oI < O) {
            const int beg = rowptr[oI];
            n = rowptr[oI + 1] - beg;
            const unsigned short* base = edgeout + (size_t)beg * 256 + lane * 4;
            int i = 0;
            for (; i + 7 < n; i += 8) {
                ushort4 v0 = *(const ushort4*)(base + (size_t)(i    ) * 256);
                ushort4 v1 = *(const ushort4*)(base + (size_t)(i + 1) * 256);
                ushort4 v2 = *(const ushort4*)(base + (size_t)(i + 2) * 256);
                ushort4 v3 = *(const ushort4*)(base + (size_t)(i + 3) * 256);
                ushort4 v4 = *(const ushort4*)(base + (size_t)(i + 4) * 256);
                ushort4 v5 = *(const ushort4*)(base + (size_t)(i + 5) * 256);
                ushort4 v6 = *(const ushort4*)(base + (size_t)(i + 6) * 256);
                ushort4 v7 = *(const ushort4*)(base + (size_t)(i + 7) * 256);
                ax += b2f(v0.x); ay += b2f(v0.y); az += b2f(v0.z); aw += b2f(v0.w);
                bx += b2f(v1.x); by += b2f(v1.y); bz += b2f(v1.z); bw += b2f(v1.w);
                ax += b2f(v2.x); ay += b2f(v2.y); az += b2f(v2.z); aw += b2f(v2.w);
                bx += b2f(v3.x); by += b2f(v3.y); bz += b2f(v3.z); bw += b2f(v3.w);
                ax += b2f(v4.x); ay += b2f(v4.y); az += b2f(v4.z); aw += b2f(v4.w);
                bx += b2f(v5.x); by += b2f(v5.y); bz += b2f(v5.z); bw += b2f(v5.w);
                ax += b2f(v6.x); ay += b2f(v6.y); az += b2f(v6.z); aw += b2f(v6.w);
                bx += b2f(v7.x); by += b2f(v7.y); bz += b2f(v7.z); bw += b2f(v7.w);
            }
            for (; i < n; ++i) {
                ushort4 v0 = *(const ushort4*)(base + (size_t)i * 256);
                ax += b2f(v0.x); ay += b2f(v0.y); az += b2f(v0.z); aw += b2f(v0.w);
            }
        }
        float inv = 1.f / fmaxf((float)n, 1.f);
        uint2 pk;
        pk.x = f2bpk((ax + bx) * inv, (ay + by) * inv);
        pk.y = f2bpk((az + bz) * inv, (aw + bw) * inv);
        unsigned byte = ((unsigned)row * 512u + (unsigned)lane * 8u) ^ (((unsigned)row & 7u) << 4);
        *(uint2*)((char*)Abuf + byte) = pk;
    }
    __syncthreads();

    f32x4 acc1[2][2][4];
    #pragma unroll
    for (int a = 0; a < 2; ++a)
        #pragma unroll
        for (int b = 0; b < 2; ++b)
            #pragma unroll
            for (int c = 0; c < 4; ++c) acc1[a][b][c] = f32x4{0.f, 0.f, 0.f, 0.f};
    #pragma unroll
    for (int ks = 0; ks < 8; ++ks) {
        const int klane = ks * 32 + ((lane >> 4) << 3);
        s16x8 af[2];
        #pragma unroll
        for (int mi = 0; mi < 2; ++mi) {
            int row = wm * 32 + mi * 16 + (lane & 15);
            af[mi] = *(const s16x8*)((const char*)Abuf + swz(row, row * 512u + klane * 2u));
        }
        #pragma unroll
        for (int nb = 0; nb < 2; ++nb)
            #pragma unroll
            for (int nj = 0; nj < 4; ++nj) {
                int col = nb * 128 + wn * 64 + nj * 16 + (lane & 15);
                s16x8 bf = *(const s16x8*)(w2aT + (long long)col * 256 + klane);
                #pragma unroll
                for (int mi = 0; mi < 2; ++mi)
                    acc1[nb][mi][nj] = __builtin_amdgcn_mfma_f32_16x16x32_bf16(af[mi], bf, acc1[nb][mi][nj], 0, 0, 0);
            }
    }
    __syncthreads();

    #pragma unroll
    for (int nb = 0; nb < 2; ++nb)
        #pragma unroll
        for (int nj = 0; nj < 4; ++nj) {
            int col = nb * 128 + wn * 64 + nj * 16 + (lane & 15);
            float bias = b2a[col];
            #pragma unroll
            for (int mi = 0; mi < 2; ++mi) {
                float r0 = fmaxf(acc1[nb][mi][nj][0] + bias, 0.f);
                float r1 = fmaxf(acc1[nb][mi][nj][1] + bias, 0.f);
                float r2 = fmaxf(acc1[nb][mi][nj][2] + bias, 0.f);
                float r3 = fmaxf(acc1[nb][mi][nj][3] + bias, 0.f);
                unsigned p01 = f2bpk(r0, r1);
                unsigned p23 = f2bpk(r2, r3);
                int rowb = wm * 32 + mi * 16 + ((lane >> 4) << 2);
                *(unsigned short*)((char*)Abuf + swz(rowb, rowb * 512u + col * 2u)) = (unsigned short)p01;
                *(unsigned short*)((char*)Abuf + swz(rowb + 1, (rowb + 1) * 512u + col * 2u)) = (unsigned short)(p01 >> 16);
                *(unsigned short*)((char*)Abuf + swz(rowb + 2, (rowb + 2) * 512u + col * 2u)) = (unsigned short)p23;
                *(unsigned short*)((char*)Abuf + swz(rowb + 3, (rowb + 3) * 512u + col * 2u)) = (unsigned short)(p23 >> 16);
            }
        }
    __syncthreads();

    f32x4 acc2[2][4];
    #pragma unroll
    for (int b = 0; b < 2; ++b)
        #pragma unroll
        for (int c = 0; c < 4; ++c) acc2[b][c] = f32x4{0.f, 0.f, 0.f, 0.f};
    #pragma unroll
    for (int ks = 0; ks < 8; ++ks) {
        const int klane = ks * 32 + ((lane >> 4) << 3);
        s16x8 af[2];
        #pragma unroll
        for (int mi = 0; mi < 2; ++mi) {
            int row = wm * 32 + mi * 16 + (lane & 15);
            af[mi] = *(const s16x8*)((const char*)Abuf + swz(row, row * 512u + klane * 2u));
        }
        #pragma unroll
        for (int nj = 0; nj < 4; ++nj) {
            int col = wn * 64 + nj * 16 + (lane & 15);
            s16x8 bf = *(const s16x8*)(w2bT + (long long)col * 256 + klane);
            #pragma unroll
            for (int mi = 0; mi < 2; ++mi)
                acc2[mi][nj] = __builtin_amdgcn_mfma_f32_16x16x32_bf16(af[mi], bf, acc2[mi][nj], 0, 0, 0);
        }
    }

    #pragma unroll
    for (int nj = 0; nj < 4; ++nj) {
        int col = wn * 64 + nj * 16 + (lane & 15);
        float bias = b2b[col];
        #pragma unroll
        for (int mi = 0; mi < 2; ++mi)
            #pragma unroll
            for (int rr = 0; rr < 4; ++rr) {
                int row = wm * 32 + mi * 16 + ((lane >> 4) << 2) + rr;
                int o = m0 + row;
                if (o < O) {
                    float v = acc2[mi][nj][rr] + bias;
                    v = v > 0.f ? v : 0.f;
                    outObj[(long long)o * 128 + col] = v;
                }
            }
    }
}

extern "C" void kernel_launch(void* const* d_in, const int* in_sizes, int n_in,
                              void* d_out, int out_size, void* d_ws, size_t ws_size,
                              hipStream_t stream) {
    const float* obj  = (const float*)d_in[0];
    const float* pred = (const float*)d_in[1];
    const int*   edges = (const int*)d_in[2];
    const float* w1a = (const float*)d_in[3];
    const float* b1a = (const float*)d_in[4];
    const float* w1b = (const float*)d_in[5];
    const float* b1b = (const float*)d_in[6];
    const float* w2a = (const float*)d_in[7];
    const float* b2a = (const float*)d_in[8];
    const float* w2b = (const float*)d_in[9];
    const float* b2b = (const float*)d_in[10];

    const int O = in_sizes[0] / 128;
    const int T = in_sizes[1] / 128;

    auto al = [](size_t x) { return (x + 255) & ~(size_t)255; };
    const size_t szEdgeout = (size_t)2 * T * 256 * 2;
    const size_t szCnt     = (size_t)O * 4;
    const size_t szRow     = (size_t)(O + 1) * 4;
    const size_t szSlot    = (size_t)T * 4;

    size_t off = 0;
    char* ws = (char*)d_ws;
    unsigned short* edgeout = (unsigned short*)(ws + off); off += al(szEdgeout);
    int* cnt    = (int*)(ws + off); off += al(szCnt);
    int* rowptr = (int*)(ws + off); off += al(szRow);
    int* slotS  = (int*)(ws + off); off += al(szSlot);
    int* slotO  = (int*)(ws + off); off += al(szSlot);
    unsigned short* w1aT = (unsigned short*)(ws + off); off += (size_t)6 * 16384 * 2;
    unsigned short* w1bT = (unsigned short*)(ws + off); off += (size_t)10 * 16384 * 2;
    unsigned short* w2aT = (unsigned short*)(ws + off); off += (size_t)256 * 256 * 2;
    unsigned short* w2bT = (unsigned short*)(ws + off);

    float* outObj = (float*)d_out;
    float* outP   = (float*)d_out + (size_t)O * 128;

    hipMemsetAsync(cnt, 0, szCnt, stream);
    const int totalT = PREP_ELEMS + T;
    prep_count_kernel<<<(totalT + 255) / 256, 256, 0, stream>>>(
        w1a, w1b, w2a, w2b, w1aT, w1bT, w2aT, w2bT, edges, cnt, slotS, slotO, T);
    scan_kernel<<<1, 1024, 0, stream>>>(cnt, rowptr, O);
    edge_mlp<<<(T + 127) / 128, 512, 0, stream>>>(obj, pred, edges, w1aT, b1a, w1bT, b1b,
                                                  slotS, slotO, rowptr, edgeout, outP, T);
    obj_mlp<<<(O + 63) / 64, 256, 0, stream>>>(edgeout, rowptr, w2aT, b2a, w2bT, b2b, outObj, O);
}